// Round 1
// baseline (804.238 us; speedup 1.0000x reference)
//
#include <hip/hip_runtime.h>
#include <math.h>

// ---------------------------------------------------------------------------
// ModularSelectCascadeNet forward, fp32 baseline.
// B=16384, M=8, NUM_LAYERS=4.
// ---------------------------------------------------------------------------

#define EPI_NONE 0
#define EPI_RELU 1
#define EPI_TANH 2
#define EPI_COND 3

// Generic tiled fp32 GEMM: C[M x N] = epi(A[M x K] @ B[K x N] + bias)
// BM=64, BN=64, BK=16, 256 threads, 4x4 micro-tile per thread.
// M is always 16384 (gridDim.y = 256). K % 16 == 0 assumed (128/400/256/64).
template<int EPI, bool RELU_A>
__global__ __launch_bounds__(256) void gemm_f32(
    const float* __restrict__ A, const float* __restrict__ Bm,
    const float* __restrict__ bias, float* __restrict__ C,
    const float* __restrict__ emb, int N, int K)
{
  __shared__ float As[16][64];
  __shared__ float Bs[16][64];
  const int tid  = threadIdx.x;
  const int ty   = tid >> 4, tx = tid & 15;
  const int row0 = blockIdx.y * 64, col0 = blockIdx.x * 64;
  const int la_row = tid >> 2, la_k = (tid & 3) << 2;   // A tile: 64 rows x 16 k
  const int lb_k   = tid >> 4, lb_col = (tid & 15) << 2; // B tile: 16 k x 64 cols
  float acc[4][4] = {};
  for (int k0 = 0; k0 < K; k0 += 16) {
    float4 a4 = *reinterpret_cast<const float4*>(&A[(size_t)(row0 + la_row) * K + k0 + la_k]);
    if (RELU_A) {
      a4.x = fmaxf(a4.x, 0.f); a4.y = fmaxf(a4.y, 0.f);
      a4.z = fmaxf(a4.z, 0.f); a4.w = fmaxf(a4.w, 0.f);
    }
    As[la_k + 0][la_row] = a4.x; As[la_k + 1][la_row] = a4.y;
    As[la_k + 2][la_row] = a4.z; As[la_k + 3][la_row] = a4.w;

    const int bc = col0 + lb_col;
    const float* Brow = Bm + (size_t)(k0 + lb_k) * N;
    float4 b4;
    if (bc + 3 < N) {
      b4 = *reinterpret_cast<const float4*>(Brow + bc);
    } else {
      b4.x = (bc + 0 < N) ? Brow[bc + 0] : 0.f;
      b4.y = (bc + 1 < N) ? Brow[bc + 1] : 0.f;
      b4.z = (bc + 2 < N) ? Brow[bc + 2] : 0.f;
      b4.w = (bc + 3 < N) ? Brow[bc + 3] : 0.f;
    }
    *reinterpret_cast<float4*>(&Bs[lb_k][lb_col]) = b4;
    __syncthreads();
    #pragma unroll
    for (int k = 0; k < 16; ++k) {
      const float4 av = *reinterpret_cast<const float4*>(&As[k][ty << 2]);
      const float4 bv = *reinterpret_cast<const float4*>(&Bs[k][tx << 2]);
      const float ar[4] = {av.x, av.y, av.z, av.w};
      const float br[4] = {bv.x, bv.y, bv.z, bv.w};
      #pragma unroll
      for (int r = 0; r < 4; ++r)
        #pragma unroll
        for (int c = 0; c < 4; ++c)
          acc[r][c] = fmaf(ar[r], br[c], acc[r][c]);
    }
    __syncthreads();
  }
  #pragma unroll
  for (int r = 0; r < 4; ++r) {
    const int row = row0 + (ty << 2) + r;
    #pragma unroll
    for (int c = 0; c < 4; ++c) {
      const int col = col0 + (tx << 2) + c;
      if (col < N) {
        float v = acc[r][c] + bias[col];
        if (EPI == EPI_RELU) v = fmaxf(v, 0.f);
        if (EPI == EPI_TANH) v = tanhf(v);
        if (EPI == EPI_COND) { v *= emb[(size_t)row * N + col]; v = fmaxf(v, 0.f); }
        C[(size_t)row * N + col] = v;
      }
    }
  }
}

// Mod einsum: H[b, m, :] = ((out[b,:]-mean1)*rstd1*g1[m,:]+b1[m,:]) @ modW[m] + modb[m]
// K=N=256, grid (4, 256, 8). Output row stride 2048, col offset m*256.
__global__ __launch_bounds__(256) void gemm_mod(
    const float* __restrict__ Xout, const float* __restrict__ mean1,
    const float* __restrict__ rstd1, const float* __restrict__ g1,
    const float* __restrict__ b1, const float* __restrict__ modW,
    const float* __restrict__ modb, float* __restrict__ H)
{
  __shared__ float As[16][64];
  __shared__ float Bs[16][64];
  const int m = blockIdx.z;
  const int tid  = threadIdx.x;
  const int ty   = tid >> 4, tx = tid & 15;
  const int row0 = blockIdx.y * 64, col0 = blockIdx.x * 64;
  const int la_row = tid >> 2, la_k = (tid & 3) << 2;
  const int lb_k   = tid >> 4, lb_col = (tid & 15) << 2;
  const float* Bp = modW + (size_t)m * 65536;
  const float* gp = g1 + m * 256;
  const float* bp = b1 + m * 256;
  const float* biasp = modb + m * 256;
  float acc[4][4] = {};
  for (int k0 = 0; k0 < 256; k0 += 16) {
    const int ka = k0 + la_k;
    float4 a4 = *reinterpret_cast<const float4*>(&Xout[(size_t)(row0 + la_row) * 256 + ka]);
    const float4 mm = *reinterpret_cast<const float4*>(&mean1[ka]);
    const float4 rr = *reinterpret_cast<const float4*>(&rstd1[ka]);
    const float4 gg = *reinterpret_cast<const float4*>(&gp[ka]);
    const float4 bb = *reinterpret_cast<const float4*>(&bp[ka]);
    a4.x = (a4.x - mm.x) * rr.x * gg.x + bb.x;
    a4.y = (a4.y - mm.y) * rr.y * gg.y + bb.y;
    a4.z = (a4.z - mm.z) * rr.z * gg.z + bb.z;
    a4.w = (a4.w - mm.w) * rr.w * gg.w + bb.w;
    As[la_k + 0][la_row] = a4.x; As[la_k + 1][la_row] = a4.y;
    As[la_k + 2][la_row] = a4.z; As[la_k + 3][la_row] = a4.w;
    *reinterpret_cast<float4*>(&Bs[lb_k][lb_col]) =
        *reinterpret_cast<const float4*>(&Bp[(size_t)(k0 + lb_k) * 256 + col0 + lb_col]);
    __syncthreads();
    #pragma unroll
    for (int k = 0; k < 16; ++k) {
      const float4 av = *reinterpret_cast<const float4*>(&As[k][ty << 2]);
      const float4 bv = *reinterpret_cast<const float4*>(&Bs[k][tx << 2]);
      const float ar[4] = {av.x, av.y, av.z, av.w};
      const float br[4] = {bv.x, bv.y, bv.z, bv.w};
      #pragma unroll
      for (int r = 0; r < 4; ++r)
        #pragma unroll
        for (int c = 0; c < 4; ++c)
          acc[r][c] = fmaf(ar[r], br[c], acc[r][c]);
    }
    __syncthreads();
  }
  #pragma unroll
  for (int r = 0; r < 4; ++r) {
    const int row = row0 + (ty << 2) + r;
    #pragma unroll
    for (int c = 0; c < 4; ++c) {
      const int col = col0 + (tx << 2) + c;
      H[(size_t)row * 2048 + m * 256 + col] = acc[r][c] + biasp[col];
    }
  }
}

// Gumbel softmax over groups of 8; one thread per (b, m).
// logit: (B,64); u: (B, u_stride) sliced at u_off; out: (B,64)
__global__ void gumbel8(const float* __restrict__ logit, const float* __restrict__ u,
                        float* __restrict__ out, int u_off, int u_stride)
{
  const int idx = blockIdx.x * 256 + threadIdx.x;   // b*8 + m
  const int b = idx >> 3, m = idx & 7;
  const float* lp = logit + (size_t)b * 64 + m * 8;
  const float* up = u + (size_t)b * u_stride + u_off + m * 8;
  float v[8];
  #pragma unroll
  for (int j = 0; j < 8; ++j) {
    const float uu = fminf(fmaxf(up[j], 1e-10f), 0.9999999f);
    v[j] = lp[j] - logf(-logf(uu));
  }
  float mx = v[0];
  #pragma unroll
  for (int j = 1; j < 8; ++j) mx = fmaxf(mx, v[j]);
  float s = 0.f;
  #pragma unroll
  for (int j = 0; j < 8; ++j) { v[j] = expf(v[j] - mx); s += v[j]; }
  const float inv = 1.f / s;
  float* op = out + (size_t)b * 64 + m * 8;
  #pragma unroll
  for (int j = 0; j < 8; ++j) op[j] = v[j] * inv;
}

// final_select = gumbel_softmax(si @ selF_W + selF_b, u_final)
// one thread per (b, j), j<8; cross-lane reduce over 8-lane groups.
__global__ void final_select_k(const float* __restrict__ si, const float* __restrict__ Wf,
                               const float* __restrict__ bias, const float* __restrict__ u,
                               float* __restrict__ fs)
{
  const int idx = blockIdx.x * 256 + threadIdx.x;
  const int b = idx >> 3, j = idx & 7;
  const float* sp = si + (size_t)b * 256;
  float acc = bias[j];
  for (int k = 0; k < 256; ++k) acc = fmaf(sp[k], Wf[k * 8 + j], acc);
  const float uu = fminf(fmaxf(u[(size_t)b * 8 + j], 1e-10f), 0.9999999f);
  float v = acc - logf(-logf(uu));
  float mx = v;
  #pragma unroll
  for (int d = 1; d < 8; d <<= 1) mx = fmaxf(mx, __shfl_xor(mx, d, 8));
  float e = expf(v - mx);
  float s = e;
  #pragma unroll
  for (int d = 1; d < 8; d <<= 1) s += __shfl_xor(s, d, 8);
  fs[(size_t)b * 8 + j] = e / s;
}

// Column sums / sumsq over 16384 rows; X is (16384, C). atomicAdd partials.
__global__ void col_stats(const float* __restrict__ X, float* __restrict__ sum,
                          float* __restrict__ sumsq, int C, int rpc)
{
  const int col = blockIdx.x * 256 + threadIdx.x;
  const int r0 = blockIdx.y * rpc;
  const float* p = X + (size_t)r0 * C + col;
  float s = 0.f, q = 0.f;
  for (int r = 0; r < rpc; ++r) {
    const float v = p[(size_t)r * C];
    s += v;
    q = fmaf(v, v, q);
  }
  atomicAdd(&sum[col], s);
  atomicAdd(&sumsq[col], q);
}

__global__ void finalize_bn1(const float* __restrict__ sum, const float* __restrict__ sumsq,
                             float* __restrict__ mean, float* __restrict__ rstd)
{
  const int i = threadIdx.x;  // 256
  const float invB = 1.f / 16384.f;
  const float m = sum[i] * invB;
  const float v = sumsq[i] * invB - m * m;
  mean[i] = m;
  rstd[i] = rsqrtf(v + 1e-5f);
}

__global__ void finalize_bn2(const float* __restrict__ sum, const float* __restrict__ sumsq,
                             const float* __restrict__ g, const float* __restrict__ b,
                             float* __restrict__ scale, float* __restrict__ shift)
{
  const int i = blockIdx.x * 256 + threadIdx.x;  // 2048
  const float invB = 1.f / 16384.f;
  const float m = sum[i] * invB;
  const float v = sumsq[i] * invB - m * m;
  const float r = rsqrtf(v + 1e-5f);
  const float sc = r * g[i];
  scale[i] = sc;
  shift[i] = b[i] - m * sc;
}

// Fused back half: bn2 apply + 3 select-cascade rounds + final_select mix + last GEMM.
// One wave per sample; lane owns 4 consecutive columns.
__global__ __launch_bounds__(256) void final_cascade(
    const float* __restrict__ H, const float* __restrict__ scale2,
    const float* __restrict__ shift2, const float* __restrict__ gs0,
    const float* __restrict__ gs1, const float* __restrict__ gs2,
    const float* __restrict__ fs, const float* __restrict__ lastW,
    const float* __restrict__ lastb, float* __restrict__ out)
{
  __shared__ float ovec[4][256];
  const int wave = threadIdx.x >> 6, lane = threadIdx.x & 63;
  const int b = blockIdx.x * 4 + wave;
  const int c0 = lane << 2;
  float prev[8][4];
  #pragma unroll
  for (int m = 0; m < 8; ++m) {
    const float4 h  = *reinterpret_cast<const float4*>(&H[(size_t)b * 2048 + m * 256 + c0]);
    const float4 sc = *reinterpret_cast<const float4*>(&scale2[m * 256 + c0]);
    const float4 sh = *reinterpret_cast<const float4*>(&shift2[m * 256 + c0]);
    prev[m][0] = h.x * sc.x + sh.x;
    prev[m][1] = h.y * sc.y + sh.y;
    prev[m][2] = h.z * sc.z + sh.z;
    prev[m][3] = h.w * sc.w + sh.w;
  }
  // selects[0]=gsels[2], [1]=gsels[1], [2]=gsels[0]
  #pragma unroll
  for (int l = 0; l < 3; ++l) {
    const float* sp = (l == 0) ? gs2 : (l == 1) ? gs1 : gs0;
    const float sv = sp[(size_t)b * 64 + lane];   // lane i holds sel[m=i/8][k=i%8]
    float nw[8][4];
    #pragma unroll
    for (int m = 0; m < 8; ++m) {
      float a0 = 0.f, a1 = 0.f, a2 = 0.f, a3 = 0.f;
      #pragma unroll
      for (int k = 0; k < 8; ++k) {
        const float s = __shfl(sv, m * 8 + k);
        a0 = fmaf(s, prev[k][0], a0);
        a1 = fmaf(s, prev[k][1], a1);
        a2 = fmaf(s, prev[k][2], a2);
        a3 = fmaf(s, prev[k][3], a3);
      }
      nw[m][0] = fmaxf(a0, 0.f); nw[m][1] = fmaxf(a1, 0.f);
      nw[m][2] = fmaxf(a2, 0.f); nw[m][3] = fmaxf(a3, 0.f);
    }
    #pragma unroll
    for (int m = 0; m < 8; ++m)
      #pragma unroll
      for (int c = 0; c < 4; ++c)
        prev[m][c] = nw[m][c];
  }
  const float fv = fs[(size_t)b * 8 + (lane & 7)];
  float ov[4] = {0.f, 0.f, 0.f, 0.f};
  #pragma unroll
  for (int m = 0; m < 8; ++m) {
    const float s = __shfl(fv, m);
    ov[0] = fmaf(s, prev[m][0], ov[0]);
    ov[1] = fmaf(s, prev[m][1], ov[1]);
    ov[2] = fmaf(s, prev[m][2], ov[2]);
    ov[3] = fmaf(s, prev[m][3], ov[3]);
  }
  #pragma unroll
  for (int c = 0; c < 4; ++c) ovec[wave][c0 + c] = ov[c];
  __syncthreads();
  if (threadIdx.x < 72) {
    const int s = threadIdx.x / 18, t = threadIdx.x % 18;
    float acc = lastb[t];
    for (int j = 0; j < 256; ++j) acc = fmaf(ovec[s][j], lastW[j * 18 + t], acc);
    out[(size_t)(blockIdx.x * 4 + s) * 18 + t] = acc;
  }
}

extern "C" void kernel_launch(void* const* d_in, const int* in_sizes, int n_in,
                              void* d_out, int out_size, void* d_ws, size_t ws_size,
                              hipStream_t stream)
{
  (void)in_sizes; (void)n_in; (void)out_size; (void)ws_size;
  const float* x       = (const float*)d_in[0];
  const float* embi    = (const float*)d_in[1];
  const float* u_sel   = (const float*)d_in[2];
  const float* u_fin   = (const float*)d_in[3];
  const float* base_W0 = (const float*)d_in[4];
  const float* base_b0 = (const float*)d_in[5];
  const float* base_W1 = (const float*)d_in[6];
  const float* base_b1 = (const float*)d_in[7];
  const float* em_W0   = (const float*)d_in[8];
  const float* em_b0   = (const float*)d_in[9];
  const float* gat_W0  = (const float*)d_in[10];
  const float* gat_b0  = (const float*)d_in[11];
  const float* gat_W1  = (const float*)d_in[12];
  const float* gat_b1  = (const float*)d_in[13];
  const float* sel_W   = (const float*)d_in[14];
  const float* sel_b   = (const float*)d_in[15];
  const float* selF_W  = (const float*)d_in[16];
  const float* selF_b  = (const float*)d_in[17];
  const float* cond_W  = (const float*)d_in[18];
  const float* cond_b  = (const float*)d_in[19];
  const float* mod_W   = (const float*)d_in[20];
  const float* mod_b   = (const float*)d_in[21];
  const float* last_W  = (const float*)d_in[22];
  const float* last_b  = (const float*)d_in[23];
  const float* bn1_g   = (const float*)d_in[24];
  const float* bn1_b   = (const float*)d_in[25];
  const float* bn2_g   = (const float*)d_in[26];
  const float* bn2_b   = (const float*)d_in[27];

  // Workspace layout (floats). h_big (16384x2048 = 33.55M f32 = 134 MB) overlaps
  // the early buffers, which are all dead before gemm_mod writes it.
  float* W = (float*)d_ws;
  float* h_big    = W;                 // [0, 33554432)
  float* bufA     = W;                 // 16384x400  (h1, then relu'd em stage 1)
  float* bufEmb   = W + 6553600;       // 16384x256  (emb, raw)
  float* bufSi    = W + 10747904;      // 16384x256  (g2relu, then select_input)
  float* bufLogit = W + 14942208;      // 16384x64
  float* bufOut   = W + 33554432;      // 16384x256  (pre-bn1 'out')
  float* gs0      = W + 37748736;      // 16384x64
  float* gs1      = gs0 + 1048576;
  float* gs2      = gs1 + 1048576;
  float* bufFs    = gs2 + 1048576;     // 16384x8
  float* stats    = bufFs + 131072;    // 9216 floats
  float* sum1   = stats;        float* sumsq1 = stats + 256;
  float* mean1  = stats + 512;  float* rstd1  = stats + 768;
  float* sum2   = stats + 1024; float* sumsq2 = stats + 3072;
  float* scale2 = stats + 5120; float* shift2 = stats + 7168;

  hipMemsetAsync(stats, 0, 9216 * sizeof(float), stream);

  const dim3 blk(256);
  // base MLP
  gemm_f32<EPI_RELU, false><<<dim3(7, 256), blk, 0, stream>>>(x, base_W0, base_b0, bufA, nullptr, 400, 128);
  gemm_f32<EPI_NONE, false><<<dim3(4, 256), blk, 0, stream>>>(bufA, base_W1, base_b1, bufOut, nullptr, 256, 400);
  // embedding / gating
  gemm_f32<EPI_RELU, false><<<dim3(7, 256), blk, 0, stream>>>(embi, em_W0, em_b0, bufA, nullptr, 400, 128);
  gemm_f32<EPI_RELU, false><<<dim3(4, 256), blk, 0, stream>>>(bufA, gat_W0, gat_b0, bufSi, nullptr, 256, 400);
  gemm_f32<EPI_NONE, false><<<dim3(4, 256), blk, 0, stream>>>(bufSi, gat_W1, gat_b1, bufEmb, nullptr, 256, 256);
  // select loop
  float* gs[3] = {gs0, gs1, gs2};
  for (int i = 0; i < 3; ++i) {
    if (i == 0)
      gemm_f32<EPI_TANH, true ><<<dim3(1, 256), blk, 0, stream>>>(bufEmb, sel_W + i * 16384, sel_b + i * 64, bufLogit, nullptr, 64, 256);
    else
      gemm_f32<EPI_TANH, false><<<dim3(1, 256), blk, 0, stream>>>(bufSi,  sel_W + i * 16384, sel_b + i * 64, bufLogit, nullptr, 64, 256);
    gumbel8<<<dim3(512), blk, 0, stream>>>(bufLogit, u_sel, gs[i], i * 64, 192);
    gemm_f32<EPI_COND, false><<<dim3(4, 256), blk, 0, stream>>>(bufLogit, cond_W + i * 16384, cond_b + i * 256, bufSi, bufEmb, 256, 64);
  }
  final_select_k<<<dim3(512), blk, 0, stream>>>(bufSi, selF_W, selF_b, u_fin, bufFs);
  // bn1 stats on 'out'
  col_stats<<<dim3(1, 64), blk, 0, stream>>>(bufOut, sum1, sumsq1, 256, 256);
  finalize_bn1<<<dim3(1), blk, 0, stream>>>(sum1, sumsq1, mean1, rstd1);
  // mod einsum (8 GEMMs) -> h_big
  gemm_mod<<<dim3(4, 256, 8), blk, 0, stream>>>(bufOut, mean1, rstd1, bn1_g, bn1_b, mod_W, mod_b, h_big);
  // bn2 stats + fold
  col_stats<<<dim3(8, 64), blk, 0, stream>>>(h_big, sum2, sumsq2, 2048, 256);
  finalize_bn2<<<dim3(8), blk, 0, stream>>>(sum2, sumsq2, bn2_g, bn2_b, scale2, shift2);
  // fused cascade + output
  final_cascade<<<dim3(4096), blk, 0, stream>>>(h_big, scale2, shift2, gs0, gs1, gs2, bufFs, last_W, last_b, (float*)d_out);
}

// Round 2
// 595.188 us; speedup vs baseline: 1.3512x; 1.3512x over previous
//
#include <hip/hip_runtime.h>
#include <math.h>

// ---------------------------------------------------------------------------
// ModularSelectCascadeNet forward. B=16384, M=8, NUM_LAYERS=4.
// R2: mod-einsum moved to bf16 MFMA (16x16x32), H stored bf16.
// ---------------------------------------------------------------------------

#define EPI_NONE 0
#define EPI_RELU 1
#define EPI_TANH 2
#define EPI_COND 3

typedef short bf16x8 __attribute__((ext_vector_type(8)));
typedef float f32x4 __attribute__((ext_vector_type(4)));
typedef unsigned short us8 __attribute__((ext_vector_type(8)));

__device__ __forceinline__ unsigned short f2bf(float f) {
  unsigned u = __float_as_uint(f);
  u += 0x7fffu + ((u >> 16) & 1u);
  return (unsigned short)(u >> 16);
}
__device__ __forceinline__ float bf2f(unsigned short h) {
  return __uint_as_float(((unsigned)h) << 16);
}
__device__ __forceinline__ void gload_lds16(const void* g, void* l) {
  __builtin_amdgcn_global_load_lds(
      (const __attribute__((address_space(1))) unsigned int*)g,
      (__attribute__((address_space(3))) unsigned int*)l, 16, 0, 0);
}

// ---------------------------------------------------------------------------
// fp32 tiled GEMM for the front chain (unchanged from R1).
template<int EPI, bool RELU_A>
__global__ __launch_bounds__(256) void gemm_f32(
    const float* __restrict__ A, const float* __restrict__ Bm,
    const float* __restrict__ bias, float* __restrict__ C,
    const float* __restrict__ emb, int N, int K)
{
  __shared__ float As[16][64];
  __shared__ float Bs[16][64];
  const int tid  = threadIdx.x;
  const int ty   = tid >> 4, tx = tid & 15;
  const int row0 = blockIdx.y * 64, col0 = blockIdx.x * 64;
  const int la_row = tid >> 2, la_k = (tid & 3) << 2;
  const int lb_k   = tid >> 4, lb_col = (tid & 15) << 2;
  float acc[4][4] = {};
  for (int k0 = 0; k0 < K; k0 += 16) {
    float4 a4 = *reinterpret_cast<const float4*>(&A[(size_t)(row0 + la_row) * K + k0 + la_k]);
    if (RELU_A) {
      a4.x = fmaxf(a4.x, 0.f); a4.y = fmaxf(a4.y, 0.f);
      a4.z = fmaxf(a4.z, 0.f); a4.w = fmaxf(a4.w, 0.f);
    }
    As[la_k + 0][la_row] = a4.x; As[la_k + 1][la_row] = a4.y;
    As[la_k + 2][la_row] = a4.z; As[la_k + 3][la_row] = a4.w;
    const int bc = col0 + lb_col;
    const float* Brow = Bm + (size_t)(k0 + lb_k) * N;
    float4 b4;
    if (bc + 3 < N) {
      b4 = *reinterpret_cast<const float4*>(Brow + bc);
    } else {
      b4.x = (bc + 0 < N) ? Brow[bc + 0] : 0.f;
      b4.y = (bc + 1 < N) ? Brow[bc + 1] : 0.f;
      b4.z = (bc + 2 < N) ? Brow[bc + 2] : 0.f;
      b4.w = (bc + 3 < N) ? Brow[bc + 3] : 0.f;
    }
    *reinterpret_cast<float4*>(&Bs[lb_k][lb_col]) = b4;
    __syncthreads();
    #pragma unroll
    for (int k = 0; k < 16; ++k) {
      const float4 av = *reinterpret_cast<const float4*>(&As[k][ty << 2]);
      const float4 bv = *reinterpret_cast<const float4*>(&Bs[k][tx << 2]);
      const float ar[4] = {av.x, av.y, av.z, av.w};
      const float br[4] = {bv.x, bv.y, bv.z, bv.w};
      #pragma unroll
      for (int r = 0; r < 4; ++r)
        #pragma unroll
        for (int c = 0; c < 4; ++c)
          acc[r][c] = fmaf(ar[r], br[c], acc[r][c]);
    }
    __syncthreads();
  }
  #pragma unroll
  for (int r = 0; r < 4; ++r) {
    const int row = row0 + (ty << 2) + r;
    #pragma unroll
    for (int c = 0; c < 4; ++c) {
      const int col = col0 + (tx << 2) + c;
      if (col < N) {
        float v = acc[r][c] + bias[col];
        if (EPI == EPI_RELU) v = fmaxf(v, 0.f);
        if (EPI == EPI_TANH) v = tanhf(v);
        if (EPI == EPI_COND) { v *= emb[(size_t)row * N + col]; v = fmaxf(v, 0.f); }
        C[(size_t)row * N + col] = v;
      }
    }
  }
}

// ---------------------------------------------------------------------------
// Conversion / fold kernels for the MFMA mod-einsum.

// xhat = (out - mean1) * rstd1, stored bf16 (16384 x 256).
__global__ __launch_bounds__(256) void bn1_apply_bf16(
    const float* __restrict__ out, const float* __restrict__ mean,
    const float* __restrict__ rstd, unsigned short* __restrict__ xb)
{
  const int i = (blockIdx.x * 256 + threadIdx.x) * 4;
  const float4 v = *reinterpret_cast<const float4*>(&out[i]);
  const int c = i & 255;
  const float4 mm = *reinterpret_cast<const float4*>(&mean[c]);
  const float4 rr = *reinterpret_cast<const float4*>(&rstd[c]);
  ushort4 o;
  o.x = f2bf((v.x - mm.x) * rr.x);
  o.y = f2bf((v.y - mm.y) * rr.y);
  o.z = f2bf((v.z - mm.z) * rr.z);
  o.w = f2bf((v.w - mm.w) * rr.w);
  *reinterpret_cast<ushort4*>(&xb[i]) = o;
}

// Wt[m][h][d] = bf16(modW[m][d][h] * g1[m][d])  (transpose + gamma fold)
__global__ __launch_bounds__(256) void fold_modw(
    const float* __restrict__ W, const float* __restrict__ g1,
    unsigned short* __restrict__ Wt)
{
  __shared__ float t[32][33];
  const int m = blockIdx.z, d0 = blockIdx.y * 32, h0 = blockIdx.x * 32;
  const int tx = threadIdx.x & 31, ty = threadIdx.x >> 5;
  #pragma unroll
  for (int k = 0; k < 4; ++k) {
    const int d = d0 + ty + k * 8;
    t[ty + k * 8][tx] = W[((size_t)m * 256 + d) * 256 + h0 + tx] * g1[m * 256 + d];
  }
  __syncthreads();
  #pragma unroll
  for (int k = 0; k < 4; ++k) {
    const int h = h0 + ty + k * 8;
    Wt[((size_t)m * 256 + h) * 256 + d0 + tx] = f2bf(t[tx][ty + k * 8]);
  }
}

// bias2[m][h] = modb[m][h] + sum_d b1[m][d] * modW[m][d][h]
__global__ void bias2_k(const float* __restrict__ W, const float* __restrict__ b1,
                        const float* __restrict__ modb, float* __restrict__ bias2)
{
  const int m = blockIdx.x, h = threadIdx.x;
  float acc = modb[m * 256 + h];
  for (int d = 0; d < 256; ++d)
    acc = fmaf(b1[m * 256 + d], W[((size_t)m * 256 + d) * 256 + h], acc);
  bias2[m * 256 + h] = acc;
}

// ---------------------------------------------------------------------------
// MFMA mod-einsum: H[b, m*256+n] = bf16( xhat[b,:] @ Wt[m][n,:]^T + bias2[m][n] )
// A: 16384x256 bf16 row-major. Wt: per-m 256(n) x 256(k) bf16 row-major.
// 128x128 tile, BK=32, 4 waves (2x2), 4x4 fragments of 16x16x32 per wave.
__global__ __launch_bounds__(256) void gemm_mod_mfma(
    const unsigned short* __restrict__ Abf, const unsigned short* __restrict__ Wt,
    const float* __restrict__ bias2, unsigned short* __restrict__ H)
{
  __shared__ unsigned short As[128 * 32];
  __shared__ unsigned short Bs[128 * 32];
  const int m = blockIdx.z;
  const int row0 = blockIdx.y * 128;
  const int n0 = blockIdx.x * 128;
  const int tid = threadIdx.x;
  const int wid = tid >> 6, lane = tid & 63;
  const int wr = wid >> 1, wc = wid & 1;
  const unsigned short* Wm = Wt + (size_t)m * 65536;

  const int arow = tid >> 2;           // 0..63
  const int kcol = (tid & 3) * 8;      // k element offset for staging
  const int lr = lane & 15, lk = (lane >> 4) * 8;

  f32x4 acc[4][4] = {};
  for (int k0 = 0; k0 < 256; k0 += 32) {
    gload_lds16(Abf + (size_t)(row0 + arow) * 256 + k0 + kcol,
                (char*)As + wid * 1024);
    gload_lds16(Abf + (size_t)(row0 + 64 + arow) * 256 + k0 + kcol,
                (char*)As + 4096 + wid * 1024);
    gload_lds16(Wm + (size_t)(n0 + arow) * 256 + k0 + kcol,
                (char*)Bs + wid * 1024);
    gload_lds16(Wm + (size_t)(n0 + 64 + arow) * 256 + k0 + kcol,
                (char*)Bs + 4096 + wid * 1024);
    __syncthreads();
    bf16x8 a[4], b[4];
    #pragma unroll
    for (int f = 0; f < 4; ++f) {
      a[f] = *reinterpret_cast<const bf16x8*>(&As[(wr * 64 + f * 16 + lr) * 32 + lk]);
      b[f] = *reinterpret_cast<const bf16x8*>(&Bs[(wc * 64 + f * 16 + lr) * 32 + lk]);
    }
    #pragma unroll
    for (int i = 0; i < 4; ++i)
      #pragma unroll
      for (int j = 0; j < 4; ++j)
        acc[i][j] = __builtin_amdgcn_mfma_f32_16x16x32_bf16(a[i], b[j], acc[i][j], 0, 0, 0);
    __syncthreads();
  }
  const int lrow = (lane >> 4) * 4;
  #pragma unroll
  for (int i = 0; i < 4; ++i) {
    #pragma unroll
    for (int j = 0; j < 4; ++j) {
      const int col = n0 + wc * 64 + j * 16 + lr;
      const float bb = bias2[m * 256 + col];
      #pragma unroll
      for (int r = 0; r < 4; ++r) {
        const int row = row0 + wr * 64 + i * 16 + lrow + r;
        H[(size_t)row * 2048 + m * 256 + col] = f2bf(acc[i][j][r] + bb);
      }
    }
  }
}

// ---------------------------------------------------------------------------
// Gumbel softmax over groups of 8; one thread per (b, m).
__global__ void gumbel8(const float* __restrict__ logit, const float* __restrict__ u,
                        float* __restrict__ out, int u_off, int u_stride)
{
  const int idx = blockIdx.x * 256 + threadIdx.x;
  const int b = idx >> 3, m = idx & 7;
  const float* lp = logit + (size_t)b * 64 + m * 8;
  const float* up = u + (size_t)b * u_stride + u_off + m * 8;
  float v[8];
  #pragma unroll
  for (int j = 0; j < 8; ++j) {
    const float uu = fminf(fmaxf(up[j], 1e-10f), 0.9999999f);
    v[j] = lp[j] - logf(-logf(uu));
  }
  float mx = v[0];
  #pragma unroll
  for (int j = 1; j < 8; ++j) mx = fmaxf(mx, v[j]);
  float s = 0.f;
  #pragma unroll
  for (int j = 0; j < 8; ++j) { v[j] = expf(v[j] - mx); s += v[j]; }
  const float inv = 1.f / s;
  float* op = out + (size_t)b * 64 + m * 8;
  #pragma unroll
  for (int j = 0; j < 8; ++j) op[j] = v[j] * inv;
}

__global__ void final_select_k(const float* __restrict__ si, const float* __restrict__ Wf,
                               const float* __restrict__ bias, const float* __restrict__ u,
                               float* __restrict__ fs)
{
  const int idx = blockIdx.x * 256 + threadIdx.x;
  const int b = idx >> 3, j = idx & 7;
  const float* sp = si + (size_t)b * 256;
  float acc = bias[j];
  for (int k = 0; k < 256; ++k) acc = fmaf(sp[k], Wf[k * 8 + j], acc);
  const float uu = fminf(fmaxf(u[(size_t)b * 8 + j], 1e-10f), 0.9999999f);
  float v = acc - logf(-logf(uu));
  float mx = v;
  #pragma unroll
  for (int d = 1; d < 8; d <<= 1) mx = fmaxf(mx, __shfl_xor(mx, d, 8));
  float e = expf(v - mx);
  float s = e;
  #pragma unroll
  for (int d = 1; d < 8; d <<= 1) s += __shfl_xor(s, d, 8);
  fs[(size_t)b * 8 + j] = e / s;
}

// fp32 column stats (for bn1 on bufOut, C=256).
__global__ void col_stats(const float* __restrict__ X, float* __restrict__ sum,
                          float* __restrict__ sumsq, int C, int rpc)
{
  const int col = blockIdx.x * 256 + threadIdx.x;
  const int r0 = blockIdx.y * rpc;
  const float* p = X + (size_t)r0 * C + col;
  float s = 0.f, q = 0.f;
  for (int r = 0; r < rpc; ++r) {
    const float v = p[(size_t)r * C];
    s += v;
    q = fmaf(v, v, q);
  }
  atomicAdd(&sum[col], s);
  atomicAdd(&sumsq[col], q);
}

// bf16 column stats for H (C=2048): thread owns 8 columns, vector loads.
__global__ __launch_bounds__(256) void col_stats_bf16(
    const unsigned short* __restrict__ X, float* __restrict__ sum,
    float* __restrict__ sumsq, int rpc)
{
  const int c0 = threadIdx.x * 8;
  const int r0 = blockIdx.y * rpc;
  float s[8] = {}, q[8] = {};
  for (int r = 0; r < rpc; ++r) {
    const us8 v = *reinterpret_cast<const us8*>(&X[(size_t)(r0 + r) * 2048 + c0]);
    #pragma unroll
    for (int j = 0; j < 8; ++j) {
      const float f = bf2f(v[j]);
      s[j] += f;
      q[j] = fmaf(f, f, q[j]);
    }
  }
  #pragma unroll
  for (int j = 0; j < 8; ++j) {
    atomicAdd(&sum[c0 + j], s[j]);
    atomicAdd(&sumsq[c0 + j], q[j]);
  }
}

__global__ void finalize_bn1(const float* __restrict__ sum, const float* __restrict__ sumsq,
                             float* __restrict__ mean, float* __restrict__ rstd)
{
  const int i = threadIdx.x;
  const float invB = 1.f / 16384.f;
  const float m = sum[i] * invB;
  const float v = sumsq[i] * invB - m * m;
  mean[i] = m;
  rstd[i] = rsqrtf(v + 1e-5f);
}

__global__ void finalize_bn2(const float* __restrict__ sum, const float* __restrict__ sumsq,
                             const float* __restrict__ g, const float* __restrict__ b,
                             float* __restrict__ scale, float* __restrict__ shift)
{
  const int i = blockIdx.x * 256 + threadIdx.x;
  const float invB = 1.f / 16384.f;
  const float m = sum[i] * invB;
  const float v = sumsq[i] * invB - m * m;
  const float r = rsqrtf(v + 1e-5f);
  const float sc = r * g[i];
  scale[i] = sc;
  shift[i] = b[i] - m * sc;
}

// Fused back half; H is bf16 now.
__global__ __launch_bounds__(256) void final_cascade(
    const unsigned short* __restrict__ H, const float* __restrict__ scale2,
    const float* __restrict__ shift2, const float* __restrict__ gs0,
    const float* __restrict__ gs1, const float* __restrict__ gs2,
    const float* __restrict__ fs, const float* __restrict__ lastW,
    const float* __restrict__ lastb, float* __restrict__ out)
{
  __shared__ float ovec[4][256];
  const int wave = threadIdx.x >> 6, lane = threadIdx.x & 63;
  const int b = blockIdx.x * 4 + wave;
  const int c0 = lane << 2;
  float prev[8][4];
  #pragma unroll
  for (int m = 0; m < 8; ++m) {
    const ushort4 h = *reinterpret_cast<const ushort4*>(&H[(size_t)b * 2048 + m * 256 + c0]);
    const float4 sc = *reinterpret_cast<const float4*>(&scale2[m * 256 + c0]);
    const float4 sh = *reinterpret_cast<const float4*>(&shift2[m * 256 + c0]);
    prev[m][0] = bf2f(h.x) * sc.x + sh.x;
    prev[m][1] = bf2f(h.y) * sc.y + sh.y;
    prev[m][2] = bf2f(h.z) * sc.z + sh.z;
    prev[m][3] = bf2f(h.w) * sc.w + sh.w;
  }
  #pragma unroll
  for (int l = 0; l < 3; ++l) {
    const float* sp = (l == 0) ? gs2 : (l == 1) ? gs1 : gs0;
    const float sv = sp[(size_t)b * 64 + lane];
    float nw[8][4];
    #pragma unroll
    for (int m = 0; m < 8; ++m) {
      float a0 = 0.f, a1 = 0.f, a2 = 0.f, a3 = 0.f;
      #pragma unroll
      for (int k = 0; k < 8; ++k) {
        const float s = __shfl(sv, m * 8 + k);
        a0 = fmaf(s, prev[k][0], a0);
        a1 = fmaf(s, prev[k][1], a1);
        a2 = fmaf(s, prev[k][2], a2);
        a3 = fmaf(s, prev[k][3], a3);
      }
      nw[m][0] = fmaxf(a0, 0.f); nw[m][1] = fmaxf(a1, 0.f);
      nw[m][2] = fmaxf(a2, 0.f); nw[m][3] = fmaxf(a3, 0.f);
    }
    #pragma unroll
    for (int m = 0; m < 8; ++m)
      #pragma unroll
      for (int c = 0; c < 4; ++c)
        prev[m][c] = nw[m][c];
  }
  const float fv = fs[(size_t)b * 8 + (lane & 7)];
  float ov[4] = {0.f, 0.f, 0.f, 0.f};
  #pragma unroll
  for (int m = 0; m < 8; ++m) {
    const float s = __shfl(fv, m);
    ov[0] = fmaf(s, prev[m][0], ov[0]);
    ov[1] = fmaf(s, prev[m][1], ov[1]);
    ov[2] = fmaf(s, prev[m][2], ov[2]);
    ov[3] = fmaf(s, prev[m][3], ov[3]);
  }
  #pragma unroll
  for (int c = 0; c < 4; ++c) ovec[wave][c0 + c] = ov[c];
  __syncthreads();
  if (threadIdx.x < 72) {
    const int s = threadIdx.x / 18, t = threadIdx.x % 18;
    float acc = lastb[t];
    for (int j = 0; j < 256; ++j) acc = fmaf(ovec[s][j], lastW[j * 18 + t], acc);
    out[(size_t)(blockIdx.x * 4 + s) * 18 + t] = acc;
  }
}

extern "C" void kernel_launch(void* const* d_in, const int* in_sizes, int n_in,
                              void* d_out, int out_size, void* d_ws, size_t ws_size,
                              hipStream_t stream)
{
  (void)in_sizes; (void)n_in; (void)out_size; (void)ws_size;
  const float* x       = (const float*)d_in[0];
  const float* embi    = (const float*)d_in[1];
  const float* u_sel   = (const float*)d_in[2];
  const float* u_fin   = (const float*)d_in[3];
  const float* base_W0 = (const float*)d_in[4];
  const float* base_b0 = (const float*)d_in[5];
  const float* base_W1 = (const float*)d_in[6];
  const float* base_b1 = (const float*)d_in[7];
  const float* em_W0   = (const float*)d_in[8];
  const float* em_b0   = (const float*)d_in[9];
  const float* gat_W0  = (const float*)d_in[10];
  const float* gat_b0  = (const float*)d_in[11];
  const float* gat_W1  = (const float*)d_in[12];
  const float* gat_b1  = (const float*)d_in[13];
  const float* sel_W   = (const float*)d_in[14];
  const float* sel_b   = (const float*)d_in[15];
  const float* selF_W  = (const float*)d_in[16];
  const float* selF_b  = (const float*)d_in[17];
  const float* cond_W  = (const float*)d_in[18];
  const float* cond_b  = (const float*)d_in[19];
  const float* mod_W   = (const float*)d_in[20];
  const float* mod_b   = (const float*)d_in[21];
  const float* last_W  = (const float*)d_in[22];
  const float* last_b  = (const float*)d_in[23];
  const float* bn1_g   = (const float*)d_in[24];
  const float* bn1_b   = (const float*)d_in[25];
  const float* bn2_g   = (const float*)d_in[26];
  const float* bn2_b   = (const float*)d_in[27];

  // Workspace layout (float offsets). h_big is now bf16 (16384x2048 ushort =
  // 16.78M float-equiv) at offset 0; overlapped early buffers are all dead
  // before gemm_mod_mfma writes it. xhat/modWt/bias2 live at 16.78M+, outside
  // h_big's span. Total footprint unchanged from R1 (~164 MB, proven).
  float* W = (float*)d_ws;
  unsigned short* h_big = (unsigned short*)W;          // [0, 16.78M) fl-equiv
  float* bufA     = W;                 // 16384x400
  float* bufEmb   = W + 6553600;       // 16384x256
  float* bufSi    = W + 10747904;      // 16384x256
  float* bufLogit = W + 14942208;      // 16384x64
  unsigned short* xhat_bf = (unsigned short*)(W + 16777216);  // 16384x256 bf16
  unsigned short* modWt   = (unsigned short*)(W + 18874368);  // 8x256x256 bf16
  float* bias2    = W + 19136512;      // 8x256
  float* bufOut   = W + 33554432;      // 16384x256 (pre-bn1 'out')
  float* gs0      = W + 37748736;      // 16384x64
  float* gs1      = gs0 + 1048576;
  float* gs2      = gs1 + 1048576;
  float* bufFs    = gs2 + 1048576;     // 16384x8
  float* stats    = bufFs + 131072;    // 9216 floats
  float* sum1   = stats;        float* sumsq1 = stats + 256;
  float* mean1  = stats + 512;  float* rstd1  = stats + 768;
  float* sum2   = stats + 1024; float* sumsq2 = stats + 3072;
  float* scale2 = stats + 5120; float* shift2 = stats + 7168;

  hipMemsetAsync(stats, 0, 9216 * sizeof(float), stream);

  const dim3 blk(256);
  // weight fold/transpose for mod einsum (independent of activations)
  fold_modw<<<dim3(8, 8, 8), blk, 0, stream>>>(mod_W, bn1_g, modWt);
  bias2_k<<<dim3(8), blk, 0, stream>>>(mod_W, bn1_b, mod_b, bias2);
  // base MLP
  gemm_f32<EPI_RELU, false><<<dim3(7, 256), blk, 0, stream>>>(x, base_W0, base_b0, bufA, nullptr, 400, 128);
  gemm_f32<EPI_NONE, false><<<dim3(4, 256), blk, 0, stream>>>(bufA, base_W1, base_b1, bufOut, nullptr, 256, 400);
  // embedding / gating
  gemm_f32<EPI_RELU, false><<<dim3(7, 256), blk, 0, stream>>>(embi, em_W0, em_b0, bufA, nullptr, 400, 128);
  gemm_f32<EPI_RELU, false><<<dim3(4, 256), blk, 0, stream>>>(bufA, gat_W0, gat_b0, bufSi, nullptr, 256, 400);
  gemm_f32<EPI_NONE, false><<<dim3(4, 256), blk, 0, stream>>>(bufSi, gat_W1, gat_b1, bufEmb, nullptr, 256, 256);
  // select loop
  float* gs[3] = {gs0, gs1, gs2};
  for (int i = 0; i < 3; ++i) {
    if (i == 0)
      gemm_f32<EPI_TANH, true ><<<dim3(1, 256), blk, 0, stream>>>(bufEmb, sel_W + i * 16384, sel_b + i * 64, bufLogit, nullptr, 64, 256);
    else
      gemm_f32<EPI_TANH, false><<<dim3(1, 256), blk, 0, stream>>>(bufSi,  sel_W + i * 16384, sel_b + i * 64, bufLogit, nullptr, 64, 256);
    gumbel8<<<dim3(512), blk, 0, stream>>>(bufLogit, u_sel, gs[i], i * 64, 192);
    gemm_f32<EPI_COND, false><<<dim3(4, 256), blk, 0, stream>>>(bufLogit, cond_W + i * 16384, cond_b + i * 256, bufSi, bufEmb, 256, 64);
  }
  final_select_k<<<dim3(512), blk, 0, stream>>>(bufSi, selF_W, selF_b, u_fin, bufFs);
  // bn1 stats + bf16 xhat
  col_stats<<<dim3(1, 128), blk, 0, stream>>>(bufOut, sum1, sumsq1, 256, 128);
  finalize_bn1<<<dim3(1), blk, 0, stream>>>(sum1, sumsq1, mean1, rstd1);
  bn1_apply_bf16<<<dim3(4096), blk, 0, stream>>>(bufOut, mean1, rstd1, xhat_bf);
  // MFMA mod einsum -> h_big (bf16)
  gemm_mod_mfma<<<dim3(2, 128, 8), blk, 0, stream>>>(xhat_bf, modWt, bias2, h_big);
  // bn2 stats + fold
  col_stats_bf16<<<dim3(1, 256), blk, 0, stream>>>(h_big, sum2, sumsq2, 64);
  finalize_bn2<<<dim3(8), blk, 0, stream>>>(sum2, sumsq2, bn2_g, bn2_b, scale2, shift2);
  // fused cascade + output
  final_cascade<<<dim3(4096), blk, 0, stream>>>(h_big, scale2, shift2, gs0, gs1, gs2, bufFs, last_W, last_b, (float*)d_out);
}

// Round 3
// 324.759 us; speedup vs baseline: 2.4764x; 1.8327x over previous
//
#include <hip/hip_runtime.h>
#include <math.h>

// ---------------------------------------------------------------------------
// ModularSelectCascadeNet forward. B=16384, M=8, NUM_LAYERS=4.
// R3: full bf16-MFMA pipeline; bn stats fused into GEMM epilogues.
// ---------------------------------------------------------------------------

#define EPI_NONE  0
#define EPI_RELU  1
#define EPI_TANH  2
#define EPI_COND  3
#define EPI_STATS 4

typedef short bf16x8 __attribute__((ext_vector_type(8)));
typedef float f32x4 __attribute__((ext_vector_type(4)));

__device__ __forceinline__ unsigned short f2bf(float f) {
  unsigned u = __float_as_uint(f);
  u += 0x7fffu + ((u >> 16) & 1u);
  return (unsigned short)(u >> 16);
}
__device__ __forceinline__ float bf2f(unsigned short h) {
  return __uint_as_float(((unsigned)h) << 16);
}
__device__ __forceinline__ void gload_lds16(const void* g, void* l) {
  __builtin_amdgcn_global_load_lds(
      (const __attribute__((address_space(1))) unsigned int*)g,
      (__attribute__((address_space(3))) unsigned int*)l, 16, 0, 0);
}
__device__ __forceinline__ bf16x8 relu_bf8(bf16x8 v) {
  bf16x8 r;
  #pragma unroll
  for (int j = 0; j < 8; ++j) r[j] = v[j] > 0 ? v[j] : (short)0;  // bf16 sign bit == int16 sign
  return r;
}

// ---------------------------------------------------------------------------
// fp32 -> bf16 convert (n multiple of 1024).
__global__ __launch_bounds__(256) void convert_bf16(
    const float* __restrict__ in, unsigned short* __restrict__ out)
{
  const int i = (blockIdx.x * 256 + threadIdx.x) * 4;
  const float4 v = *reinterpret_cast<const float4*>(&in[i]);
  ushort4 o;
  o.x = f2bf(v.x); o.y = f2bf(v.y); o.z = f2bf(v.z); o.w = f2bf(v.w);
  *reinterpret_cast<ushort4*>(&out[i]) = o;
}

// Transpose + convert + zero-pad: W fp32 [K][N] -> Wt bf16 [NP][KP].
// grid (KP/32, NP/32), 256 threads.
__global__ __launch_bounds__(256) void transpose_w(
    const float* __restrict__ W, unsigned short* __restrict__ Wt,
    int K, int N, int KP, int NP)
{
  __shared__ float t[32][33];
  const int k0 = blockIdx.x * 32, n0 = blockIdx.y * 32;
  const int tx = threadIdx.x & 31, ty = threadIdx.x >> 5;
  #pragma unroll
  for (int p = 0; p < 4; ++p) {
    const int k = k0 + ty + p * 8;
    t[ty + p * 8][tx] = (k < K && n0 + tx < N) ? W[(size_t)k * N + n0 + tx] : 0.f;
  }
  __syncthreads();
  #pragma unroll
  for (int p = 0; p < 4; ++p) {
    const int n = n0 + ty + p * 8;
    Wt[(size_t)n * KP + k0 + tx] = f2bf(t[tx][ty + p * 8]);
  }
}

// modWt[m][h][d] = bf16(modW[m][d][h] * rstd[d] * g1[m][d])
__global__ __launch_bounds__(256) void fold_modw(
    const float* __restrict__ W, const float* __restrict__ g1,
    const float* __restrict__ rstd, unsigned short* __restrict__ Wt)
{
  __shared__ float t[32][33];
  const int m = blockIdx.z, d0 = blockIdx.y * 32, h0 = blockIdx.x * 32;
  const int tx = threadIdx.x & 31, ty = threadIdx.x >> 5;
  #pragma unroll
  for (int p = 0; p < 4; ++p) {
    const int d = d0 + ty + p * 8;
    t[ty + p * 8][tx] = W[((size_t)m * 256 + d) * 256 + h0 + tx] * rstd[d] * g1[m * 256 + d];
  }
  __syncthreads();
  #pragma unroll
  for (int p = 0; p < 4; ++p) {
    const int h = h0 + ty + p * 8;
    Wt[((size_t)m * 256 + h) * 256 + d0 + tx] = f2bf(t[tx][ty + p * 8]);
  }
}

// bias2[m][h] = modb[m][h] + sum_d (b1[m][d] - mean[d]*rstd[d]*g1[m][d]) * modW[m][d][h]
__global__ void bias2_k(const float* __restrict__ W, const float* __restrict__ b1,
                        const float* __restrict__ modb, const float* __restrict__ mean,
                        const float* __restrict__ rstd, const float* __restrict__ g1,
                        float* __restrict__ bias2)
{
  const int m = blockIdx.x, h = threadIdx.x;
  float acc = modb[m * 256 + h];
  for (int d = 0; d < 256; ++d) {
    const float c = b1[m * 256 + d] - mean[d] * rstd[d] * g1[m * 256 + d];
    acc = fmaf(c, W[((size_t)m * 256 + d) * 256 + h], acc);
  }
  bias2[m * 256 + h] = acc;
}

// ---------------------------------------------------------------------------
// Generic bf16 MFMA GEMM. BM=128 fixed, BK=32.
// C[row, col] = epi(A[row,:] @ Wt[col,:] + bias[col]); A: [16384][AS] bf16,
// Wt: [>=gridx*BN][K] bf16 (pad rows/cols zeroed), C: bf16 stride CS.
template<int BN, int WM, int WN, int EPI, bool RELU_A>
__global__ __launch_bounds__(256) void gemm_bf16(
    const unsigned short* __restrict__ A, int AS,
    const unsigned short* __restrict__ Wt, const float* __restrict__ bias,
    unsigned short* __restrict__ C, int CS, int Nreal, int NP, int K,
    const unsigned short* __restrict__ emb,
    float* __restrict__ sum, float* __restrict__ sumsq)
{
  constexpr int FRAG_M = 128 / WM / 16;
  constexpr int FRAG_N = BN / WN / 16;
  __shared__ unsigned short As[128 * 32];
  __shared__ unsigned short Bs[BN * 32];
  const int row0 = blockIdx.y * 128;
  const int n0 = blockIdx.x * BN;
  const int tid = threadIdx.x;
  const int wid = tid >> 6, lane = tid & 63;
  const int wr = wid / WN, wc = wid % WN;
  const int arow = tid >> 2;
  const int kcol = (tid & 3) * 8;
  const int lr = lane & 15, lk = (lane >> 4) * 8;
  const int lrow = (lane >> 4) * 4;

  f32x4 acc[FRAG_M][FRAG_N] = {};
  for (int k0 = 0; k0 < K; k0 += 32) {
    gload_lds16(A + (size_t)(row0 + arow) * AS + k0 + kcol, (char*)As + tid * 16);
    gload_lds16(A + (size_t)(row0 + 64 + arow) * AS + k0 + kcol, (char*)As + 4096 + tid * 16);
    gload_lds16(Wt + (size_t)(n0 + arow) * K + k0 + kcol, (char*)Bs + tid * 16);
    if constexpr (BN == 128)
      gload_lds16(Wt + (size_t)(n0 + 64 + arow) * K + k0 + kcol, (char*)Bs + 4096 + tid * 16);
    __syncthreads();
    bf16x8 a[FRAG_M], b[FRAG_N];
    #pragma unroll
    for (int i = 0; i < FRAG_M; ++i) {
      a[i] = *reinterpret_cast<const bf16x8*>(&As[(wr * (128 / WM) + i * 16 + lr) * 32 + lk]);
      if (RELU_A) a[i] = relu_bf8(a[i]);
    }
    #pragma unroll
    for (int j = 0; j < FRAG_N; ++j)
      b[j] = *reinterpret_cast<const bf16x8*>(&Bs[(wc * (BN / WN) + j * 16 + lr) * 32 + lk]);
    #pragma unroll
    for (int i = 0; i < FRAG_M; ++i)
      #pragma unroll
      for (int j = 0; j < FRAG_N; ++j)
        acc[i][j] = __builtin_amdgcn_mfma_f32_16x16x32_bf16(a[i], b[j], acc[i][j], 0, 0, 0);
    __syncthreads();
  }
  #pragma unroll
  for (int j = 0; j < FRAG_N; ++j) {
    const int col = n0 + wc * (BN / WN) + j * 16 + lr;
    if (col >= NP) continue;
    const bool real = col < Nreal;
    const float bv = real ? bias[col] : 0.f;
    float s = 0.f, q = 0.f;
    #pragma unroll
    for (int i = 0; i < FRAG_M; ++i) {
      #pragma unroll
      for (int r = 0; r < 4; ++r) {
        const int row = row0 + wr * (128 / WM) + i * 16 + lrow + r;
        float v = acc[i][j][r] + bv;
        if (EPI == EPI_RELU) v = fmaxf(v, 0.f);
        if (EPI == EPI_TANH) v = tanhf(v);
        if (EPI == EPI_COND) { v *= bf2f(emb[(size_t)row * 256 + col]); v = fmaxf(v, 0.f); }
        if (!real) v = 0.f;
        const unsigned short hv = f2bf(v);
        C[(size_t)row * CS + col] = hv;
        if (EPI == EPI_STATS) {
          const float vr = bf2f(hv);
          s += vr;
          q = fmaf(vr, vr, q);
        }
      }
    }
    if (EPI == EPI_STATS) {
      s += __shfl_xor(s, 16); s += __shfl_xor(s, 32);
      q += __shfl_xor(q, 16); q += __shfl_xor(q, 32);
      if (lane < 16) {
        atomicAdd(&sum[col], s);
        atomicAdd(&sumsq[col], q);
      }
    }
  }
}

// ---------------------------------------------------------------------------
// MFMA mod-einsum with fused bn2 stats:
// H[b, m*256+n] = bf16( out_bf[b,:] @ modWt[m][n,:] + bias2[m][n] )
__global__ __launch_bounds__(256) void gemm_mod_mfma(
    const unsigned short* __restrict__ Abf, const unsigned short* __restrict__ Wt,
    const float* __restrict__ bias2, unsigned short* __restrict__ H,
    float* __restrict__ sum, float* __restrict__ sumsq)
{
  __shared__ unsigned short As[128 * 32];
  __shared__ unsigned short Bs[128 * 32];
  const int m = blockIdx.z;
  const int row0 = blockIdx.y * 128;
  const int n0 = blockIdx.x * 128;
  const int tid = threadIdx.x;
  const int wid = tid >> 6, lane = tid & 63;
  const int wr = wid >> 1, wc = wid & 1;
  const unsigned short* Wm = Wt + (size_t)m * 65536;
  const int arow = tid >> 2;
  const int kcol = (tid & 3) * 8;
  const int lr = lane & 15, lk = (lane >> 4) * 8;
  const int lrow = (lane >> 4) * 4;

  f32x4 acc[4][4] = {};
  for (int k0 = 0; k0 < 256; k0 += 32) {
    gload_lds16(Abf + (size_t)(row0 + arow) * 256 + k0 + kcol, (char*)As + tid * 16);
    gload_lds16(Abf + (size_t)(row0 + 64 + arow) * 256 + k0 + kcol, (char*)As + 4096 + tid * 16);
    gload_lds16(Wm + (size_t)(n0 + arow) * 256 + k0 + kcol, (char*)Bs + tid * 16);
    gload_lds16(Wm + (size_t)(n0 + 64 + arow) * 256 + k0 + kcol, (char*)Bs + 4096 + tid * 16);
    __syncthreads();
    bf16x8 a[4], b[4];
    #pragma unroll
    for (int f = 0; f < 4; ++f) {
      a[f] = *reinterpret_cast<const bf16x8*>(&As[(wr * 64 + f * 16 + lr) * 32 + lk]);
      b[f] = *reinterpret_cast<const bf16x8*>(&Bs[(wc * 64 + f * 16 + lr) * 32 + lk]);
    }
    #pragma unroll
    for (int i = 0; i < 4; ++i)
      #pragma unroll
      for (int j = 0; j < 4; ++j)
        acc[i][j] = __builtin_amdgcn_mfma_f32_16x16x32_bf16(a[i], b[j], acc[i][j], 0, 0, 0);
    __syncthreads();
  }
  #pragma unroll
  for (int j = 0; j < 4; ++j) {
    const int col = n0 + wc * 64 + j * 16 + lr;
    const int gcol = m * 256 + col;
    const float bb = bias2[gcol];
    float s = 0.f, q = 0.f;
    #pragma unroll
    for (int i = 0; i < 4; ++i) {
      #pragma unroll
      for (int r = 0; r < 4; ++r) {
        const int row = row0 + wr * 64 + i * 16 + lrow + r;
        const unsigned short hv = f2bf(acc[i][j][r] + bb);
        H[(size_t)row * 2048 + gcol] = hv;
        const float vr = bf2f(hv);
        s += vr;
        q = fmaf(vr, vr, q);
      }
    }
    s += __shfl_xor(s, 16); s += __shfl_xor(s, 32);
    q += __shfl_xor(q, 16); q += __shfl_xor(q, 32);
    if (lane < 16) {
      atomicAdd(&sum[gcol], s);
      atomicAdd(&sumsq[gcol], q);
    }
  }
}

// ---------------------------------------------------------------------------
// Gumbel softmax over groups of 8 (bf16 logits).
__global__ void gumbel8(const unsigned short* __restrict__ logit, const float* __restrict__ u,
                        float* __restrict__ out, int u_off, int u_stride)
{
  const int idx = blockIdx.x * 256 + threadIdx.x;
  const int b = idx >> 3, m = idx & 7;
  const unsigned short* lp = logit + (size_t)b * 64 + m * 8;
  const float* up = u + (size_t)b * u_stride + u_off + m * 8;
  float v[8];
  #pragma unroll
  for (int j = 0; j < 8; ++j) {
    const float uu = fminf(fmaxf(up[j], 1e-10f), 0.9999999f);
    v[j] = bf2f(lp[j]) - logf(-logf(uu));
  }
  float mx = v[0];
  #pragma unroll
  for (int j = 1; j < 8; ++j) mx = fmaxf(mx, v[j]);
  float s = 0.f;
  #pragma unroll
  for (int j = 0; j < 8; ++j) { v[j] = expf(v[j] - mx); s += v[j]; }
  const float inv = 1.f / s;
  float* op = out + (size_t)b * 64 + m * 8;
  #pragma unroll
  for (int j = 0; j < 8; ++j) op[j] = v[j] * inv;
}

__global__ void final_select_k(const unsigned short* __restrict__ si, const float* __restrict__ Wf,
                               const float* __restrict__ bias, const float* __restrict__ u,
                               float* __restrict__ fs)
{
  const int idx = blockIdx.x * 256 + threadIdx.x;
  const int b = idx >> 3, j = idx & 7;
  const unsigned short* sp = si + (size_t)b * 256;
  float acc = bias[j];
  for (int k = 0; k < 256; ++k) acc = fmaf(bf2f(sp[k]), Wf[k * 8 + j], acc);
  const float uu = fminf(fmaxf(u[(size_t)b * 8 + j], 1e-10f), 0.9999999f);
  float v = acc - logf(-logf(uu));
  float mx = v;
  #pragma unroll
  for (int d = 1; d < 8; d <<= 1) mx = fmaxf(mx, __shfl_xor(mx, d, 8));
  float e = expf(v - mx);
  float s = e;
  #pragma unroll
  for (int d = 1; d < 8; d <<= 1) s += __shfl_xor(s, d, 8);
  fs[(size_t)b * 8 + j] = e / s;
}

__global__ void finalize_bn1(const float* __restrict__ sum, const float* __restrict__ sumsq,
                             float* __restrict__ mean, float* __restrict__ rstd)
{
  const int i = threadIdx.x;
  const float invB = 1.f / 16384.f;
  const float m = sum[i] * invB;
  const float v = sumsq[i] * invB - m * m;
  mean[i] = m;
  rstd[i] = rsqrtf(v + 1e-5f);
}

__global__ void finalize_bn2(const float* __restrict__ sum, const float* __restrict__ sumsq,
                             const float* __restrict__ g, const float* __restrict__ b,
                             float* __restrict__ scale, float* __restrict__ shift)
{
  const int i = blockIdx.x * 256 + threadIdx.x;
  const float invB = 1.f / 16384.f;
  const float m = sum[i] * invB;
  const float v = sumsq[i] * invB - m * m;
  const float r = rsqrtf(v + 1e-5f);
  const float sc = r * g[i];
  scale[i] = sc;
  shift[i] = b[i] - m * sc;
}

// Fused back half (H bf16).
__global__ __launch_bounds__(256) void final_cascade(
    const unsigned short* __restrict__ H, const float* __restrict__ scale2,
    const float* __restrict__ shift2, const float* __restrict__ gs0,
    const float* __restrict__ gs1, const float* __restrict__ gs2,
    const float* __restrict__ fs, const float* __restrict__ lastW,
    const float* __restrict__ lastb, float* __restrict__ out)
{
  __shared__ float ovec[4][256];
  const int wave = threadIdx.x >> 6, lane = threadIdx.x & 63;
  const int b = blockIdx.x * 4 + wave;
  const int c0 = lane << 2;
  float prev[8][4];
  #pragma unroll
  for (int m = 0; m < 8; ++m) {
    const ushort4 h = *reinterpret_cast<const ushort4*>(&H[(size_t)b * 2048 + m * 256 + c0]);
    const float4 sc = *reinterpret_cast<const float4*>(&scale2[m * 256 + c0]);
    const float4 sh = *reinterpret_cast<const float4*>(&shift2[m * 256 + c0]);
    prev[m][0] = bf2f(h.x) * sc.x + sh.x;
    prev[m][1] = bf2f(h.y) * sc.y + sh.y;
    prev[m][2] = bf2f(h.z) * sc.z + sh.z;
    prev[m][3] = bf2f(h.w) * sc.w + sh.w;
  }
  #pragma unroll
  for (int l = 0; l < 3; ++l) {
    const float* sp = (l == 0) ? gs2 : (l == 1) ? gs1 : gs0;
    const float sv = sp[(size_t)b * 64 + lane];
    float nw[8][4];
    #pragma unroll
    for (int m = 0; m < 8; ++m) {
      float a0 = 0.f, a1 = 0.f, a2 = 0.f, a3 = 0.f;
      #pragma unroll
      for (int k = 0; k < 8; ++k) {
        const float s = __shfl(sv, m * 8 + k);
        a0 = fmaf(s, prev[k][0], a0);
        a1 = fmaf(s, prev[k][1], a1);
        a2 = fmaf(s, prev[k][2], a2);
        a3 = fmaf(s, prev[k][3], a3);
      }
      nw[m][0] = fmaxf(a0, 0.f); nw[m][1] = fmaxf(a1, 0.f);
      nw[m][2] = fmaxf(a2, 0.f); nw[m][3] = fmaxf(a3, 0.f);
    }
    #pragma unroll
    for (int m = 0; m < 8; ++m)
      #pragma unroll
      for (int c = 0; c < 4; ++c)
        prev[m][c] = nw[m][c];
  }
  const float fv = fs[(size_t)b * 8 + (lane & 7)];
  float ov[4] = {0.f, 0.f, 0.f, 0.f};
  #pragma unroll
  for (int m = 0; m < 8; ++m) {
    const float s = __shfl(fv, m);
    ov[0] = fmaf(s, prev[m][0], ov[0]);
    ov[1] = fmaf(s, prev[m][1], ov[1]);
    ov[2] = fmaf(s, prev[m][2], ov[2]);
    ov[3] = fmaf(s, prev[m][3], ov[3]);
  }
  #pragma unroll
  for (int c = 0; c < 4; ++c) ovec[wave][c0 + c] = ov[c];
  __syncthreads();
  if (threadIdx.x < 72) {
    const int s = threadIdx.x / 18, t = threadIdx.x % 18;
    float acc = lastb[t];
    for (int j = 0; j < 256; ++j) acc = fmaf(ovec[s][j], lastW[j * 18 + t], acc);
    out[(size_t)(blockIdx.x * 4 + s) * 18 + t] = acc;
  }
}

extern "C" void kernel_launch(void* const* d_in, const int* in_sizes, int n_in,
                              void* d_out, int out_size, void* d_ws, size_t ws_size,
                              hipStream_t stream)
{
  (void)in_sizes; (void)n_in; (void)out_size; (void)ws_size;
  const float* x       = (const float*)d_in[0];
  const float* embi    = (const float*)d_in[1];
  const float* u_sel   = (const float*)d_in[2];
  const float* u_fin   = (const float*)d_in[3];
  const float* base_W0 = (const float*)d_in[4];
  const float* base_b0 = (const float*)d_in[5];
  const float* base_W1 = (const float*)d_in[6];
  const float* base_b1 = (const float*)d_in[7];
  const float* em_W0   = (const float*)d_in[8];
  const float* em_b0   = (const float*)d_in[9];
  const float* gat_W0  = (const float*)d_in[10];
  const float* gat_b0  = (const float*)d_in[11];
  const float* gat_W1  = (const float*)d_in[12];
  const float* gat_b1  = (const float*)d_in[13];
  const float* sel_W   = (const float*)d_in[14];
  const float* sel_b   = (const float*)d_in[15];
  const float* selF_W  = (const float*)d_in[16];
  const float* selF_b  = (const float*)d_in[17];
  const float* cond_W  = (const float*)d_in[18];
  const float* cond_b  = (const float*)d_in[19];
  const float* mod_W   = (const float*)d_in[20];
  const float* mod_b   = (const float*)d_in[21];
  const float* last_W  = (const float*)d_in[22];
  const float* last_b  = (const float*)d_in[23];
  const float* bn1_g   = (const float*)d_in[24];
  const float* bn1_b   = (const float*)d_in[25];
  const float* bn2_g   = (const float*)d_in[26];
  const float* bn2_b   = (const float*)d_in[27];

  // --- workspace layout (byte offsets) ---
  char* WSB = (char*)d_ws;
  unsigned short* h_big    = (unsigned short*)(WSB + 0);          // 16384x2048 bf16
  unsigned short* h1       = (unsigned short*)(WSB + 67108864);   // 16384x416 bf16
  unsigned short* x_bf     = (unsigned short*)(WSB + 80740352);   // 16384x128
  unsigned short* e_bf     = (unsigned short*)(WSB + 84934656);   // 16384x128
  unsigned short* emb_bf   = (unsigned short*)(WSB + 89128960);   // 16384x256
  unsigned short* si_bf    = (unsigned short*)(WSB + 97517568);   // 16384x256
  unsigned short* out_bf   = (unsigned short*)(WSB + 105906176);  // 16384x256
  unsigned short* logit_bf = (unsigned short*)(WSB + 114294784);  // 16384x64
  float* gs0   = (float*)(WSB + 116391936);  // 16384x64
  float* gs1   = (float*)(WSB + 120586240);
  float* gs2   = (float*)(WSB + 124780544);
  float* bufFs = (float*)(WSB + 128974848);  // 16384x8
  unsigned short* W0t   = (unsigned short*)(WSB + 129499136);  // 512x128
  unsigned short* emW0t = (unsigned short*)(WSB + 129630208);  // 512x128
  unsigned short* W1t   = (unsigned short*)(WSB + 129761280);  // 256x416
  unsigned short* g0t   = (unsigned short*)(WSB + 129974272);  // 256x416
  unsigned short* g1t   = (unsigned short*)(WSB + 130187264);  // 256x256
  unsigned short* selWt = (unsigned short*)(WSB + 130318336);  // 3x64x256
  unsigned short* condWt= (unsigned short*)(WSB + 130416640);  // 3x256x64
  unsigned short* modWt = (unsigned short*)(WSB + 130514944);  // 8x256x256
  float* bias2 = (float*)(WSB + 131563520);  // 8x256
  float* stats = (float*)(WSB + 131571712);  // 9216 floats
  float* sum1   = stats;        float* sumsq1 = stats + 256;
  float* mean1  = stats + 512;  float* rstd1  = stats + 768;
  float* sum2   = stats + 1024; float* sumsq2 = stats + 3072;
  float* scale2 = stats + 5120; float* shift2 = stats + 7168;

  hipMemsetAsync(stats, 0, 9216 * sizeof(float), stream);

  const dim3 blk(256);
  // input + weight conversion
  convert_bf16<<<dim3(2048), blk, 0, stream>>>(x, x_bf);
  convert_bf16<<<dim3(2048), blk, 0, stream>>>(embi, e_bf);
  transpose_w<<<dim3(4, 16), blk, 0, stream>>>(base_W0, W0t, 128, 400, 128, 512);
  transpose_w<<<dim3(4, 16), blk, 0, stream>>>(em_W0, emW0t, 128, 400, 128, 512);
  transpose_w<<<dim3(13, 8), blk, 0, stream>>>(base_W1, W1t, 400, 256, 416, 256);
  transpose_w<<<dim3(13, 8), blk, 0, stream>>>(gat_W0, g0t, 400, 256, 416, 256);
  transpose_w<<<dim3(8, 8), blk, 0, stream>>>(gat_W1, g1t, 256, 256, 256, 256);
  for (int i = 0; i < 3; ++i) {
    transpose_w<<<dim3(8, 2), blk, 0, stream>>>(sel_W + i * 16384, selWt + i * 16384, 256, 64, 256, 64);
    transpose_w<<<dim3(2, 8), blk, 0, stream>>>(cond_W + i * 16384, condWt + i * 16384, 64, 256, 64, 256);
  }

  // base MLP: x -> relu -> out (with fused bn1 stats)
  gemm_bf16<128, 2, 2, EPI_RELU, false><<<dim3(4, 128), blk, 0, stream>>>(
      x_bf, 128, W0t, base_b0, h1, 416, 400, 416, 128, nullptr, nullptr, nullptr);
  gemm_bf16<128, 2, 2, EPI_STATS, false><<<dim3(2, 128), blk, 0, stream>>>(
      h1, 416, W1t, base_b1, out_bf, 256, 256, 256, 416, nullptr, sum1, sumsq1);
  // embedding / gating
  gemm_bf16<128, 2, 2, EPI_RELU, false><<<dim3(4, 128), blk, 0, stream>>>(
      e_bf, 128, emW0t, em_b0, h1, 416, 400, 416, 128, nullptr, nullptr, nullptr);
  gemm_bf16<128, 2, 2, EPI_RELU, false><<<dim3(2, 128), blk, 0, stream>>>(
      h1, 416, g0t, gat_b0, si_bf, 256, 256, 256, 416, nullptr, nullptr, nullptr);
  gemm_bf16<128, 2, 2, EPI_NONE, false><<<dim3(2, 128), blk, 0, stream>>>(
      si_bf, 256, g1t, gat_b1, emb_bf, 256, 256, 256, 256, nullptr, nullptr, nullptr);
  // select loop
  float* gs[3] = {gs0, gs1, gs2};
  for (int i = 0; i < 3; ++i) {
    if (i == 0)
      gemm_bf16<64, 4, 1, EPI_TANH, true><<<dim3(1, 128), blk, 0, stream>>>(
          emb_bf, 256, selWt, sel_b, logit_bf, 64, 64, 64, 256, nullptr, nullptr, nullptr);
    else
      gemm_bf16<64, 4, 1, EPI_TANH, false><<<dim3(1, 128), blk, 0, stream>>>(
          si_bf, 256, selWt + i * 16384, sel_b + i * 64, logit_bf, 64, 64, 64, 256, nullptr, nullptr, nullptr);
    gumbel8<<<dim3(512), blk, 0, stream>>>(logit_bf, u_sel, gs[i], i * 64, 192);
    gemm_bf16<128, 2, 2, EPI_COND, false><<<dim3(2, 128), blk, 0, stream>>>(
        logit_bf, 64, condWt + i * 16384, cond_b + i * 256, si_bf, 256, 256, 256, 64, emb_bf, nullptr, nullptr);
  }
  final_select_k<<<dim3(512), blk, 0, stream>>>(si_bf, selF_W, selF_b, u_fin, bufFs);
  // bn1 finalize + weight fold for mod einsum
  finalize_bn1<<<dim3(1), blk, 0, stream>>>(sum1, sumsq1, mean1, rstd1);
  fold_modw<<<dim3(8, 8, 8), blk, 0, stream>>>(mod_W, bn1_g, rstd1, modWt);
  bias2_k<<<dim3(8), blk, 0, stream>>>(mod_W, bn1_b, mod_b, mean1, rstd1, bn1_g, bias2);
  // MFMA mod einsum -> h_big (bf16), fused bn2 stats
  gemm_mod_mfma<<<dim3(2, 128, 8), blk, 0, stream>>>(out_bf, modWt, bias2, h_big, sum2, sumsq2);
  finalize_bn2<<<dim3(8), blk, 0, stream>>>(sum2, sumsq2, bn2_g, bn2_b, scale2, shift2);
  // fused cascade + output
  final_cascade<<<dim3(4096), blk, 0, stream>>>(h_big, scale2, shift2, gs0, gs1, gs2, bufFs, last_W, last_b, (float*)d_out);
}

// Round 4
// 289.885 us; speedup vs baseline: 2.7743x; 1.1203x over previous
//
#include <hip/hip_runtime.h>
#include <math.h>

// ---------------------------------------------------------------------------
// ModularSelectCascadeNet forward. B=16384, M=8, NUM_LAYERS=4.
// R4: cascade rewritten (uniform scalar sel loads, in-wave last GEMM, no LDS);
//     all prep fused into one kernel; bn finalize inlined; 19 dispatches.
// ---------------------------------------------------------------------------

#define EPI_NONE  0
#define EPI_RELU  1
#define EPI_TANH  2
#define EPI_COND  3
#define EPI_STATS 4

typedef short bf16x8 __attribute__((ext_vector_type(8)));
typedef float f32x4 __attribute__((ext_vector_type(4)));

__device__ __forceinline__ unsigned short f2bf(float f) {
  unsigned u = __float_as_uint(f);
  u += 0x7fffu + ((u >> 16) & 1u);
  return (unsigned short)(u >> 16);
}
__device__ __forceinline__ float bf2f(unsigned short h) {
  return __uint_as_float(((unsigned)h) << 16);
}
__device__ __forceinline__ void gload_lds16(const void* g, void* l) {
  __builtin_amdgcn_global_load_lds(
      (const __attribute__((address_space(1))) unsigned int*)g,
      (__attribute__((address_space(3))) unsigned int*)l, 16, 0, 0);
}
__device__ __forceinline__ bf16x8 relu_bf8(bf16x8 v) {
  bf16x8 r;
  #pragma unroll
  for (int j = 0; j < 8; ++j) r[j] = v[j] > 0 ? v[j] : (short)0;
  return r;
}

// ---------------------------------------------------------------------------
// Fused prep: converts x/emb to bf16, transposes all static weights to bf16
// [N][K] layout (zero-padded), transposes lastW to f32 [18->32][256], zeroes
// the stats accumulators. One launch, 4601 blocks.
__global__ __launch_bounds__(256) void prep_all(
    const float* __restrict__ x, const float* __restrict__ embi,
    const float* __restrict__ base_W0, const float* __restrict__ em_W0,
    const float* __restrict__ base_W1, const float* __restrict__ gat_W0,
    const float* __restrict__ gat_W1, const float* __restrict__ sel_W,
    const float* __restrict__ cond_W, const float* __restrict__ last_W,
    unsigned short* __restrict__ x_bf, unsigned short* __restrict__ e_bf,
    unsigned short* __restrict__ W0t, unsigned short* __restrict__ emW0t,
    unsigned short* __restrict__ W1t, unsigned short* __restrict__ g0t,
    unsigned short* __restrict__ g1t, unsigned short* __restrict__ selWt,
    unsigned short* __restrict__ condWt, float* __restrict__ lastWt,
    float* __restrict__ stats)
{
  __shared__ float t[32][33];
  int bid = blockIdx.x;
  const int tid = threadIdx.x;

  if (bid < 4096) {  // fp32 -> bf16 converts (16384 x 128 each)
    const float* src = bid < 2048 ? x : embi;
    unsigned short* dst = bid < 2048 ? x_bf : e_bf;
    const int i = ((bid & 2047) * 256 + tid) * 4;
    const float4 v = *reinterpret_cast<const float4*>(&src[i]);
    ushort4 o;
    o.x = f2bf(v.x); o.y = f2bf(v.y); o.z = f2bf(v.z); o.w = f2bf(v.w);
    *reinterpret_cast<ushort4*>(&dst[i]) = o;
    return;
  }
  bid -= 4096;

  const int tx = tid & 31, ty = tid >> 5;

  if (bid < 496) {  // bf16 weight transposes: W[K][N] -> Wt[NP][KP]
    const float* src; unsigned short* dst; int K, N, KP, gx, local;
    if (bid < 64)       { src = base_W0; dst = W0t;   K = 128; N = 400; KP = 128; gx = 4;  local = bid; }
    else if (bid < 128) { src = em_W0;   dst = emW0t; K = 128; N = 400; KP = 128; gx = 4;  local = bid - 64; }
    else if (bid < 232) { src = base_W1; dst = W1t;   K = 400; N = 256; KP = 416; gx = 13; local = bid - 128; }
    else if (bid < 336) { src = gat_W0;  dst = g0t;   K = 400; N = 256; KP = 416; gx = 13; local = bid - 232; }
    else if (bid < 400) { src = gat_W1;  dst = g1t;   K = 256; N = 256; KP = 256; gx = 8;  local = bid - 336; }
    else if (bid < 448) {
      const int i = (bid - 400) / 16;
      src = sel_W + i * 16384; dst = selWt + i * 16384;
      K = 256; N = 64; KP = 256; gx = 8; local = (bid - 400) % 16;
    } else {
      const int i = (bid - 448) / 16;
      src = cond_W + i * 16384; dst = condWt + i * 16384;
      K = 64; N = 256; KP = 64; gx = 2; local = (bid - 448) % 16;
    }
    const int k0 = (local % gx) * 32, n0 = (local / gx) * 32;
    #pragma unroll
    for (int p = 0; p < 4; ++p) {
      const int k = k0 + ty + p * 8;
      t[ty + p * 8][tx] = (k < K && n0 + tx < N) ? src[(size_t)k * N + n0 + tx] : 0.f;
    }
    __syncthreads();
    #pragma unroll
    for (int p = 0; p < 4; ++p) {
      const int n = n0 + ty + p * 8;
      dst[(size_t)n * KP + k0 + tx] = f2bf(t[tx][ty + p * 8]);
    }
    return;
  }
  bid -= 496;

  if (bid < 8) {  // lastW f32 transpose: [256][18] -> [32][256] (rows 18+ zero)
    const int k0 = bid * 32;
    #pragma unroll
    for (int p = 0; p < 4; ++p)
      t[ty + p * 8][tx] = (tx < 18) ? last_W[(size_t)(k0 + ty + p * 8) * 18 + tx] : 0.f;
    __syncthreads();
    #pragma unroll
    for (int p = 0; p < 4; ++p)
      lastWt[(size_t)(ty + p * 8) * 256 + k0 + tx] = t[tx][ty + p * 8];
    return;
  }

  // zero stats (4608 floats)
  for (int i = tid; i < 4608; i += 256) stats[i] = 0.f;
}

// ---------------------------------------------------------------------------
// Generic bf16 MFMA GEMM. BM=128 fixed, BK=32.
template<int BN, int WM, int WN, int EPI, bool RELU_A>
__global__ __launch_bounds__(256) void gemm_bf16(
    const unsigned short* __restrict__ A, int AS,
    const unsigned short* __restrict__ Wt, const float* __restrict__ bias,
    unsigned short* __restrict__ C, int CS, int Nreal, int NP, int K,
    const unsigned short* __restrict__ emb,
    float* __restrict__ sum, float* __restrict__ sumsq)
{
  constexpr int FRAG_M = 128 / WM / 16;
  constexpr int FRAG_N = BN / WN / 16;
  __shared__ unsigned short As[128 * 32];
  __shared__ unsigned short Bs[BN * 32];
  const int row0 = blockIdx.y * 128;
  const int n0 = blockIdx.x * BN;
  const int tid = threadIdx.x;
  const int wid = tid >> 6, lane = tid & 63;
  const int wr = wid / WN, wc = wid % WN;
  const int arow = tid >> 2;
  const int kcol = (tid & 3) * 8;
  const int lr = lane & 15, lk = (lane >> 4) * 8;
  const int lrow = (lane >> 4) * 4;

  f32x4 acc[FRAG_M][FRAG_N] = {};
  for (int k0 = 0; k0 < K; k0 += 32) {
    gload_lds16(A + (size_t)(row0 + arow) * AS + k0 + kcol, (char*)As + tid * 16);
    gload_lds16(A + (size_t)(row0 + 64 + arow) * AS + k0 + kcol, (char*)As + 4096 + tid * 16);
    gload_lds16(Wt + (size_t)(n0 + arow) * K + k0 + kcol, (char*)Bs + tid * 16);
    if constexpr (BN == 128)
      gload_lds16(Wt + (size_t)(n0 + 64 + arow) * K + k0 + kcol, (char*)Bs + 4096 + tid * 16);
    __syncthreads();
    bf16x8 a[FRAG_M], b[FRAG_N];
    #pragma unroll
    for (int i = 0; i < FRAG_M; ++i) {
      a[i] = *reinterpret_cast<const bf16x8*>(&As[(wr * (128 / WM) + i * 16 + lr) * 32 + lk]);
      if (RELU_A) a[i] = relu_bf8(a[i]);
    }
    #pragma unroll
    for (int j = 0; j < FRAG_N; ++j)
      b[j] = *reinterpret_cast<const bf16x8*>(&Bs[(wc * (BN / WN) + j * 16 + lr) * 32 + lk]);
    #pragma unroll
    for (int i = 0; i < FRAG_M; ++i)
      #pragma unroll
      for (int j = 0; j < FRAG_N; ++j)
        acc[i][j] = __builtin_amdgcn_mfma_f32_16x16x32_bf16(a[i], b[j], acc[i][j], 0, 0, 0);
    __syncthreads();
  }
  #pragma unroll
  for (int j = 0; j < FRAG_N; ++j) {
    const int col = n0 + wc * (BN / WN) + j * 16 + lr;
    if (col >= NP) continue;
    const bool real = col < Nreal;
    const float bv = real ? bias[col] : 0.f;
    float s = 0.f, q = 0.f;
    #pragma unroll
    for (int i = 0; i < FRAG_M; ++i) {
      #pragma unroll
      for (int r = 0; r < 4; ++r) {
        const int row = row0 + wr * (128 / WM) + i * 16 + lrow + r;
        float v = acc[i][j][r] + bv;
        if (EPI == EPI_RELU) v = fmaxf(v, 0.f);
        if (EPI == EPI_TANH) v = tanhf(v);
        if (EPI == EPI_COND) { v *= bf2f(emb[(size_t)row * 256 + col]); v = fmaxf(v, 0.f); }
        if (!real) v = 0.f;
        const unsigned short hv = f2bf(v);
        C[(size_t)row * CS + col] = hv;
        if (EPI == EPI_STATS) {
          const float vr = bf2f(hv);
          s += vr;
          q = fmaf(vr, vr, q);
        }
      }
    }
    if (EPI == EPI_STATS) {
      s += __shfl_xor(s, 16); s += __shfl_xor(s, 32);
      q += __shfl_xor(q, 16); q += __shfl_xor(q, 32);
      if (lane < 16) {
        atomicAdd(&sum[col], s);
        atomicAdd(&sumsq[col], q);
      }
    }
  }
}

// ---------------------------------------------------------------------------
// Gumbel softmax over groups of 8 (bf16 logits).
__global__ void gumbel8(const unsigned short* __restrict__ logit, const float* __restrict__ u,
                        float* __restrict__ out, int u_off, int u_stride)
{
  const int idx = blockIdx.x * 256 + threadIdx.x;
  const int b = idx >> 3, m = idx & 7;
  const unsigned short* lp = logit + (size_t)b * 64 + m * 8;
  const float* up = u + (size_t)b * u_stride + u_off + m * 8;
  float v[8];
  #pragma unroll
  for (int j = 0; j < 8; ++j) {
    const float uu = fminf(fmaxf(up[j], 1e-10f), 0.9999999f);
    v[j] = bf2f(lp[j]) - logf(-logf(uu));
  }
  float mx = v[0];
  #pragma unroll
  for (int j = 1; j < 8; ++j) mx = fmaxf(mx, v[j]);
  float s = 0.f;
  #pragma unroll
  for (int j = 0; j < 8; ++j) { v[j] = expf(v[j] - mx); s += v[j]; }
  const float inv = 1.f / s;
  float* op = out + (size_t)b * 64 + m * 8;
  #pragma unroll
  for (int j = 0; j < 8; ++j) op[j] = v[j] * inv;
}

__global__ void final_select_k(const unsigned short* __restrict__ si, const float* __restrict__ Wf,
                               const float* __restrict__ bias, const float* __restrict__ u,
                               float* __restrict__ fs)
{
  const int idx = blockIdx.x * 256 + threadIdx.x;
  const int b = idx >> 3, j = idx & 7;
  const unsigned short* sp = si + (size_t)b * 256;
  float acc = bias[j];
  for (int k = 0; k < 256; ++k) acc = fmaf(bf2f(sp[k]), Wf[k * 8 + j], acc);
  const float uu = fminf(fmaxf(u[(size_t)b * 8 + j], 1e-10f), 0.9999999f);
  float v = acc - logf(-logf(uu));
  float mx = v;
  #pragma unroll
  for (int d = 1; d < 8; d <<= 1) mx = fmaxf(mx, __shfl_xor(mx, d, 8));
  float e = expf(v - mx);
  float s = e;
  #pragma unroll
  for (int d = 1; d < 8; d <<= 1) s += __shfl_xor(s, d, 8);
  fs[(size_t)b * 8 + j] = e / s;
}

// ---------------------------------------------------------------------------
// Fold mod weights with inline bn1 finalize. grid (8, 8, 9):
//  z<8 : modWt[m][h][d] = bf16(modW[m][d][h] * rstd1[d] * g1[m][d])
//  z==8, y==0: bias2[m][h] = modb[m][h] + sum_d (b1-mean*rstd*g1)[m][d]*W[m][d][h]
__global__ __launch_bounds__(256) void fold_modw_all(
    const float* __restrict__ W, const float* __restrict__ g1,
    const float* __restrict__ b1, const float* __restrict__ modb,
    const float* __restrict__ sum1, const float* __restrict__ sumsq1,
    unsigned short* __restrict__ Wt, float* __restrict__ bias2)
{
  const float invB = 1.f / 16384.f;
  if (blockIdx.z == 8) {
    if (blockIdx.y != 0) return;
    const int m = blockIdx.x, h = threadIdx.x;
    float acc = modb[m * 256 + h];
    for (int d = 0; d < 256; ++d) {
      const float mean = sum1[d] * invB;
      const float var = sumsq1[d] * invB - mean * mean;
      const float r = rsqrtf(var + 1e-5f);
      const float c = b1[m * 256 + d] - mean * r * g1[m * 256 + d];
      acc = fmaf(c, W[((size_t)m * 256 + d) * 256 + h], acc);
    }
    bias2[m * 256 + h] = acc;
    return;
  }
  __shared__ float t[32][33];
  const int m = blockIdx.z, d0 = blockIdx.y * 32, h0 = blockIdx.x * 32;
  const int tx = threadIdx.x & 31, ty = threadIdx.x >> 5;
  #pragma unroll
  for (int p = 0; p < 4; ++p) {
    const int d = d0 + ty + p * 8;
    const float mean = sum1[d] * invB;
    const float var = sumsq1[d] * invB - mean * mean;
    const float r = rsqrtf(var + 1e-5f);
    t[ty + p * 8][tx] = W[((size_t)m * 256 + d) * 256 + h0 + tx] * r * g1[m * 256 + d];
  }
  __syncthreads();
  #pragma unroll
  for (int p = 0; p < 4; ++p) {
    const int h = h0 + ty + p * 8;
    Wt[((size_t)m * 256 + h) * 256 + d0 + tx] = f2bf(t[tx][ty + p * 8]);
  }
}

// ---------------------------------------------------------------------------
// Fused back half: inline bn2 finalize + 3 cascade rounds + final mix + last
// GEMM. One wave per sample, no LDS, no block sync. Select weights are
// wave-uniform -> scalar loads via readfirstlane'd sample index.
__global__ __launch_bounds__(256) void final_cascade(
    const unsigned short* __restrict__ H, const float* __restrict__ sum2,
    const float* __restrict__ sumsq2, const float* __restrict__ g2,
    const float* __restrict__ b2, const float* __restrict__ gs0,
    const float* __restrict__ gs1, const float* __restrict__ gs2,
    const float* __restrict__ fs, const float* __restrict__ lastWt,
    const float* __restrict__ lastb, float* __restrict__ out)
{
  const int wave = threadIdx.x >> 6, lane = threadIdx.x & 63;
  const int b = __builtin_amdgcn_readfirstlane(blockIdx.x * 4 + wave);
  const int c0 = lane << 2;
  const float invB = 1.f / 16384.f;

  float prev[8][4];
  #pragma unroll
  for (int m = 0; m < 8; ++m) {
    const int gc = m * 256 + c0;
    const ushort4 h = *reinterpret_cast<const ushort4*>(&H[(size_t)b * 2048 + gc]);
    const float4 s4 = *reinterpret_cast<const float4*>(&sum2[gc]);
    const float4 q4 = *reinterpret_cast<const float4*>(&sumsq2[gc]);
    const float4 gg = *reinterpret_cast<const float4*>(&g2[gc]);
    const float4 bb = *reinterpret_cast<const float4*>(&b2[gc]);
    const float hv[4] = {bf2f(h.x), bf2f(h.y), bf2f(h.z), bf2f(h.w)};
    const float sv[4] = {s4.x, s4.y, s4.z, s4.w};
    const float qv[4] = {q4.x, q4.y, q4.z, q4.w};
    const float gv[4] = {gg.x, gg.y, gg.z, gg.w};
    const float bv[4] = {bb.x, bb.y, bb.z, bb.w};
    #pragma unroll
    for (int c = 0; c < 4; ++c) {
      const float mean = sv[c] * invB;
      const float var = qv[c] * invB - mean * mean;
      const float sc = rsqrtf(var + 1e-5f) * gv[c];
      prev[m][c] = (hv[c] - mean) * sc + bv[c];
    }
  }

  const float* sel0 = gs2 + (size_t)b * 64;  // selects[0] = gsels[2]
  const float* sel1 = gs1 + (size_t)b * 64;
  const float* sel2 = gs0 + (size_t)b * 64;
  #pragma unroll
  for (int l = 0; l < 3; ++l) {
    const float* sp = (l == 0) ? sel0 : (l == 1) ? sel1 : sel2;
    float nw[8][4];
    #pragma unroll
    for (int m = 0; m < 8; ++m) {
      float a0 = 0.f, a1 = 0.f, a2 = 0.f, a3 = 0.f;
      #pragma unroll
      for (int k = 0; k < 8; ++k) {
        const float s = sp[m * 8 + k];   // wave-uniform load
        a0 = fmaf(s, prev[k][0], a0);
        a1 = fmaf(s, prev[k][1], a1);
        a2 = fmaf(s, prev[k][2], a2);
        a3 = fmaf(s, prev[k][3], a3);
      }
      nw[m][0] = fmaxf(a0, 0.f); nw[m][1] = fmaxf(a1, 0.f);
      nw[m][2] = fmaxf(a2, 0.f); nw[m][3] = fmaxf(a3, 0.f);
    }
    #pragma unroll
    for (int m = 0; m < 8; ++m)
      #pragma unroll
      for (int c = 0; c < 4; ++c)
        prev[m][c] = nw[m][c];
  }

  const float* fp = fs + (size_t)b * 8;
  float ov[4] = {0.f, 0.f, 0.f, 0.f};
  #pragma unroll
  for (int m = 0; m < 8; ++m) {
    const float s = fp[m];               // wave-uniform load
    ov[0] = fmaf(s, prev[m][0], ov[0]);
    ov[1] = fmaf(s, prev[m][1], ov[1]);
    ov[2] = fmaf(s, prev[m][2], ov[2]);
    ov[3] = fmaf(s, prev[m][3], ov[3]);
  }

  // last GEMM: out[b][t] = ovec . lastWt[t] + lastb[t], wave-reduced.
  #pragma unroll
  for (int t = 0; t < 18; ++t) {
    const float4 w = *reinterpret_cast<const float4*>(&lastWt[t * 256 + c0]);
    float p = fmaf(ov[0], w.x, fmaf(ov[1], w.y, fmaf(ov[2], w.z, ov[3] * w.w)));
    #pragma unroll
    for (int d = 1; d < 64; d <<= 1) p += __shfl_xor(p, d);
    if (lane == 0) out[(size_t)b * 18 + t] = p + lastb[t];
  }
}

extern "C" void kernel_launch(void* const* d_in, const int* in_sizes, int n_in,
                              void* d_out, int out_size, void* d_ws, size_t ws_size,
                              hipStream_t stream)
{
  (void)in_sizes; (void)n_in; (void)out_size; (void)ws_size;
  const float* x       = (const float*)d_in[0];
  const float* embi    = (const float*)d_in[1];
  const float* u_sel   = (const float*)d_in[2];
  const float* u_fin   = (const float*)d_in[3];
  const float* base_W0 = (const float*)d_in[4];
  const float* base_b0 = (const float*)d_in[5];
  const float* base_W1 = (const float*)d_in[6];
  const float* base_b1 = (const float*)d_in[7];
  const float* em_W0   = (const float*)d_in[8];
  const float* em_b0   = (const float*)d_in[9];
  const float* gat_W0  = (const float*)d_in[10];
  const float* gat_b0  = (const float*)d_in[11];
  const float* gat_W1  = (const float*)d_in[12];
  const float* gat_b1  = (const float*)d_in[13];
  const float* sel_W   = (const float*)d_in[14];
  const float* sel_b   = (const float*)d_in[15];
  const float* selF_W  = (const float*)d_in[16];
  const float* selF_b  = (const float*)d_in[17];
  const float* cond_W  = (const float*)d_in[18];
  const float* cond_b  = (const float*)d_in[19];
  const float* mod_W   = (const float*)d_in[20];
  const float* mod_b   = (const float*)d_in[21];
  const float* last_W  = (const float*)d_in[22];
  const float* last_b  = (const float*)d_in[23];
  const float* bn1_g   = (const float*)d_in[24];
  const float* bn1_b   = (const float*)d_in[25];
  const float* bn2_g   = (const float*)d_in[26];
  const float* bn2_b   = (const float*)d_in[27];

  // --- workspace layout (byte offsets) ---
  char* WSB = (char*)d_ws;
  unsigned short* h_big    = (unsigned short*)(WSB + 0);          // 16384x2048 bf16
  unsigned short* h1       = (unsigned short*)(WSB + 67108864);   // 16384x416
  unsigned short* x_bf     = (unsigned short*)(WSB + 80740352);   // 16384x128
  unsigned short* e_bf     = (unsigned short*)(WSB + 84934656);   // 16384x128
  unsigned short* emb_bf   = (unsigned short*)(WSB + 89128960);   // 16384x256
  unsigned short* si_bf    = (unsigned short*)(WSB + 97517568);   // 16384x256
  unsigned short* out_bf   = (unsigned short*)(WSB + 105906176);  // 16384x256
  unsigned short* logit_bf = (unsigned short*)(WSB + 114294784);  // 16384x64
  float* gs0   = (float*)(WSB + 116391936);  // 16384x64
  float* gs1   = (float*)(WSB + 120586240);
  float* gs2   = (float*)(WSB + 124780544);
  float* bufFs = (float*)(WSB + 128974848);  // 16384x8
  unsigned short* W0t   = (unsigned short*)(WSB + 129499136);  // 512x128
  unsigned short* emW0t = (unsigned short*)(WSB + 129630208);  // 512x128
  unsigned short* W1t   = (unsigned short*)(WSB + 129761280);  // 256x416
  unsigned short* g0t   = (unsigned short*)(WSB + 129974272);  // 256x416
  unsigned short* g1t   = (unsigned short*)(WSB + 130187264);  // 256x256
  unsigned short* selWt = (unsigned short*)(WSB + 130318336);  // 3x64x256
  unsigned short* condWt= (unsigned short*)(WSB + 130416640);  // 3x256x64
  unsigned short* modWt = (unsigned short*)(WSB + 130514944);  // 8x256x256
  float* bias2  = (float*)(WSB + 131563520);  // 2048
  float* stats  = (float*)(WSB + 131571712);  // 4608 floats
  float* lastWt = (float*)(WSB + 131590144);  // 32x256 f32
  float* sum1   = stats;        float* sumsq1 = stats + 256;
  float* sum2   = stats + 512;  float* sumsq2 = stats + 2560;

  const dim3 blk(256);
  // fused prep (converts + weight transposes + stats zero)
  prep_all<<<dim3(4601), blk, 0, stream>>>(
      x, embi, base_W0, em_W0, base_W1, gat_W0, gat_W1, sel_W, cond_W, last_W,
      x_bf, e_bf, W0t, emW0t, W1t, g0t, g1t, selWt, condWt, lastWt, stats);

  // base MLP: x -> relu -> out (fused bn1 stats)
  gemm_bf16<128, 2, 2, EPI_RELU, false><<<dim3(4, 128), blk, 0, stream>>>(
      x_bf, 128, W0t, base_b0, h1, 416, 400, 416, 128, nullptr, nullptr, nullptr);
  gemm_bf16<128, 2, 2, EPI_STATS, false><<<dim3(2, 128), blk, 0, stream>>>(
      h1, 416, W1t, base_b1, out_bf, 256, 256, 256, 416, nullptr, sum1, sumsq1);
  // embedding / gating
  gemm_bf16<128, 2, 2, EPI_RELU, false><<<dim3(4, 128), blk, 0, stream>>>(
      e_bf, 128, emW0t, em_b0, h1, 416, 400, 416, 128, nullptr, nullptr, nullptr);
  gemm_bf16<128, 2, 2, EPI_RELU, false><<<dim3(2, 128), blk, 0, stream>>>(
      h1, 416, g0t, gat_b0, si_bf, 256, 256, 256, 416, nullptr, nullptr, nullptr);
  gemm_bf16<128, 2, 2, EPI_NONE, false><<<dim3(2, 128), blk, 0, stream>>>(
      si_bf, 256, g1t, gat_b1, emb_bf, 256, 256, 256, 256, nullptr, nullptr, nullptr);
  // select loop
  float* gs[3] = {gs0, gs1, gs2};
  for (int i = 0; i < 3; ++i) {
    if (i == 0)
      gemm_bf16<64, 4, 1, EPI_TANH, true><<<dim3(1, 128), blk, 0, stream>>>(
          emb_bf, 256, selWt, sel_b, logit_bf, 64, 64, 64, 256, nullptr, nullptr, nullptr);
    else
      gemm_bf16<64, 4, 1, EPI_TANH, false><<<dim3(1, 128), blk, 0, stream>>>(
          si_bf, 256, selWt + i * 16384, sel_b + i * 64, logit_bf, 64, 64, 64, 256, nullptr, nullptr, nullptr);
    gumbel8<<<dim3(512), blk, 0, stream>>>(logit_bf, u_sel, gs[i], i * 64, 192);
    gemm_bf16<128, 2, 2, EPI_COND, false><<<dim3(2, 128), blk, 0, stream>>>(
        logit_bf, 64, condWt + i * 16384, cond_b + i * 256, si_bf, 256, 256, 256, 64, emb_bf, nullptr, nullptr);
  }
  final_select_k<<<dim3(512), blk, 0, stream>>>(si_bf, selF_W, selF_b, u_fin, bufFs);
  // bn1 finalize + mod weight fold + bias2 (one kernel)
  fold_modw_all<<<dim3(8, 8, 9), blk, 0, stream>>>(
      mod_W, bn1_g, bn1_b, mod_b, sum1, sumsq1, modWt, bias2);
  // mod einsum as one 16384 x 2048 x 256 GEMM (fused bn2 stats)
  gemm_bf16<128, 2, 2, EPI_STATS, false><<<dim3(16, 128), blk, 0, stream>>>(
      out_bf, 256, modWt, bias2, h_big, 2048, 2048, 2048, 256, nullptr, sum2, sumsq2);
  // fused cascade + inline bn2 + last GEMM
  final_cascade<<<dim3(4096), blk, 0, stream>>>(
      h_big, sum2, sumsq2, bn2_g, bn2_b, gs0, gs1, gs2, bufFs, lastWt, last_b, (float*)d_out);
}

// Round 5
// 267.953 us; speedup vs baseline: 3.0014x; 1.0818x over previous
//
#include <hip/hip_runtime.h>
#include <math.h>

// ---------------------------------------------------------------------------
// ModularSelectCascadeNet forward. B=16384, M=8, NUM_LAYERS=4.
// R5: cascade slimmed (precomputed bn2 scale/shift, ovec->bf16, last GEMM as
//     separate MFMA kernel). 21 dispatches.
// ---------------------------------------------------------------------------

#define EPI_NONE  0
#define EPI_RELU  1
#define EPI_TANH  2
#define EPI_COND  3
#define EPI_STATS 4

typedef short bf16x8 __attribute__((ext_vector_type(8)));
typedef float f32x4 __attribute__((ext_vector_type(4)));

__device__ __forceinline__ unsigned short f2bf(float f) {
  unsigned u = __float_as_uint(f);
  u += 0x7fffu + ((u >> 16) & 1u);
  return (unsigned short)(u >> 16);
}
__device__ __forceinline__ float bf2f(unsigned short h) {
  return __uint_as_float(((unsigned)h) << 16);
}
__device__ __forceinline__ void gload_lds16(const void* g, void* l) {
  __builtin_amdgcn_global_load_lds(
      (const __attribute__((address_space(1))) unsigned int*)g,
      (__attribute__((address_space(3))) unsigned int*)l, 16, 0, 0);
}
__device__ __forceinline__ bf16x8 relu_bf8(bf16x8 v) {
  bf16x8 r;
  #pragma unroll
  for (int j = 0; j < 8; ++j) r[j] = v[j] > 0 ? v[j] : (short)0;
  return r;
}

// ---------------------------------------------------------------------------
// Fused prep: converts x/emb to bf16, transposes all weights to bf16 [N][K]
// (zero-padded), lastW -> bf16 [64][256] (rows 18..63 zero), zeroes stats.
__global__ __launch_bounds__(256) void prep_all(
    const float* __restrict__ x, const float* __restrict__ embi,
    const float* __restrict__ base_W0, const float* __restrict__ em_W0,
    const float* __restrict__ base_W1, const float* __restrict__ gat_W0,
    const float* __restrict__ gat_W1, const float* __restrict__ sel_W,
    const float* __restrict__ cond_W, const float* __restrict__ last_W,
    unsigned short* __restrict__ x_bf, unsigned short* __restrict__ e_bf,
    unsigned short* __restrict__ W0t, unsigned short* __restrict__ emW0t,
    unsigned short* __restrict__ W1t, unsigned short* __restrict__ g0t,
    unsigned short* __restrict__ g1t, unsigned short* __restrict__ selWt,
    unsigned short* __restrict__ condWt, unsigned short* __restrict__ lastWt,
    float* __restrict__ stats)
{
  __shared__ float t[32][33];
  int bid = blockIdx.x;
  const int tid = threadIdx.x;

  if (bid < 4096) {  // fp32 -> bf16 converts
    const float* src = bid < 2048 ? x : embi;
    unsigned short* dst = bid < 2048 ? x_bf : e_bf;
    const int i = ((bid & 2047) * 256 + tid) * 4;
    const float4 v = *reinterpret_cast<const float4*>(&src[i]);
    ushort4 o;
    o.x = f2bf(v.x); o.y = f2bf(v.y); o.z = f2bf(v.z); o.w = f2bf(v.w);
    *reinterpret_cast<ushort4*>(&dst[i]) = o;
    return;
  }
  bid -= 4096;

  const int tx = tid & 31, ty = tid >> 5;

  if (bid < 496) {  // bf16 weight transposes: W[K][N] -> Wt[NP][KP]
    const float* src; unsigned short* dst; int K, N, KP, gx, local;
    if (bid < 64)       { src = base_W0; dst = W0t;   K = 128; N = 400; KP = 128; gx = 4;  local = bid; }
    else if (bid < 128) { src = em_W0;   dst = emW0t; K = 128; N = 400; KP = 128; gx = 4;  local = bid - 64; }
    else if (bid < 232) { src = base_W1; dst = W1t;   K = 400; N = 256; KP = 416; gx = 13; local = bid - 128; }
    else if (bid < 336) { src = gat_W0;  dst = g0t;   K = 400; N = 256; KP = 416; gx = 13; local = bid - 232; }
    else if (bid < 400) { src = gat_W1;  dst = g1t;   K = 256; N = 256; KP = 256; gx = 8;  local = bid - 336; }
    else if (bid < 448) {
      const int i = (bid - 400) / 16;
      src = sel_W + i * 16384; dst = selWt + i * 16384;
      K = 256; N = 64; KP = 256; gx = 8; local = (bid - 400) % 16;
    } else {
      const int i = (bid - 448) / 16;
      src = cond_W + i * 16384; dst = condWt + i * 16384;
      K = 64; N = 256; KP = 64; gx = 2; local = (bid - 448) % 16;
    }
    const int k0 = (local % gx) * 32, n0 = (local / gx) * 32;
    #pragma unroll
    for (int p = 0; p < 4; ++p) {
      const int k = k0 + ty + p * 8;
      t[ty + p * 8][tx] = (k < K && n0 + tx < N) ? src[(size_t)k * N + n0 + tx] : 0.f;
    }
    __syncthreads();
    #pragma unroll
    for (int p = 0; p < 4; ++p) {
      const int n = n0 + ty + p * 8;
      dst[(size_t)n * KP + k0 + tx] = f2bf(t[tx][ty + p * 8]);
    }
    return;
  }
  bid -= 496;

  if (bid < 8) {  // lastW: [256][18] -> bf16 [64][256], rows 18..63 zero
    const int k0 = bid * 32;
    #pragma unroll
    for (int p = 0; p < 4; ++p)
      t[ty + p * 8][tx] = (tx < 18) ? last_W[(size_t)(k0 + ty + p * 8) * 18 + tx] : 0.f;
    __syncthreads();
    #pragma unroll
    for (int p = 0; p < 4; ++p) {
      const int n = ty + p * 8;                       // 0..31
      lastWt[(size_t)n * 256 + k0 + tx] = f2bf(t[tx][n]);
      lastWt[(size_t)(n + 32) * 256 + k0 + tx] = 0;   // rows 32..63
    }
    return;
  }

  // zero stats (4608 floats)
  for (int i = tid; i < 4608; i += 256) stats[i] = 0.f;
}

// ---------------------------------------------------------------------------
// Generic bf16 MFMA GEMM. BM=128 fixed, BK=32.
template<int BN, int WM, int WN, int EPI, bool RELU_A>
__global__ __launch_bounds__(256) void gemm_bf16(
    const unsigned short* __restrict__ A, int AS,
    const unsigned short* __restrict__ Wt, const float* __restrict__ bias,
    unsigned short* __restrict__ C, int CS, int Nreal, int NP, int K,
    const unsigned short* __restrict__ emb,
    float* __restrict__ sum, float* __restrict__ sumsq)
{
  constexpr int FRAG_M = 128 / WM / 16;
  constexpr int FRAG_N = BN / WN / 16;
  __shared__ unsigned short As[128 * 32];
  __shared__ unsigned short Bs[BN * 32];
  const int row0 = blockIdx.y * 128;
  const int n0 = blockIdx.x * BN;
  const int tid = threadIdx.x;
  const int wid = tid >> 6, lane = tid & 63;
  const int wr = wid / WN, wc = wid % WN;
  const int arow = tid >> 2;
  const int kcol = (tid & 3) * 8;
  const int lr = lane & 15, lk = (lane >> 4) * 8;
  const int lrow = (lane >> 4) * 4;

  f32x4 acc[FRAG_M][FRAG_N] = {};
  for (int k0 = 0; k0 < K; k0 += 32) {
    gload_lds16(A + (size_t)(row0 + arow) * AS + k0 + kcol, (char*)As + tid * 16);
    gload_lds16(A + (size_t)(row0 + 64 + arow) * AS + k0 + kcol, (char*)As + 4096 + tid * 16);
    gload_lds16(Wt + (size_t)(n0 + arow) * K + k0 + kcol, (char*)Bs + tid * 16);
    if constexpr (BN == 128)
      gload_lds16(Wt + (size_t)(n0 + 64 + arow) * K + k0 + kcol, (char*)Bs + 4096 + tid * 16);
    __syncthreads();
    bf16x8 a[FRAG_M], b[FRAG_N];
    #pragma unroll
    for (int i = 0; i < FRAG_M; ++i) {
      a[i] = *reinterpret_cast<const bf16x8*>(&As[(wr * (128 / WM) + i * 16 + lr) * 32 + lk]);
      if (RELU_A) a[i] = relu_bf8(a[i]);
    }
    #pragma unroll
    for (int j = 0; j < FRAG_N; ++j)
      b[j] = *reinterpret_cast<const bf16x8*>(&Bs[(wc * (BN / WN) + j * 16 + lr) * 32 + lk]);
    #pragma unroll
    for (int i = 0; i < FRAG_M; ++i)
      #pragma unroll
      for (int j = 0; j < FRAG_N; ++j)
        acc[i][j] = __builtin_amdgcn_mfma_f32_16x16x32_bf16(a[i], b[j], acc[i][j], 0, 0, 0);
    __syncthreads();
  }
  #pragma unroll
  for (int j = 0; j < FRAG_N; ++j) {
    const int col = n0 + wc * (BN / WN) + j * 16 + lr;
    if (col >= NP) continue;
    const bool real = col < Nreal;
    const float bv = real ? bias[col] : 0.f;
    float s = 0.f, q = 0.f;
    #pragma unroll
    for (int i = 0; i < FRAG_M; ++i) {
      #pragma unroll
      for (int r = 0; r < 4; ++r) {
        const int row = row0 + wr * (128 / WM) + i * 16 + lrow + r;
        float v = acc[i][j][r] + bv;
        if (EPI == EPI_RELU) v = fmaxf(v, 0.f);
        if (EPI == EPI_TANH) v = tanhf(v);
        if (EPI == EPI_COND) { v *= bf2f(emb[(size_t)row * 256 + col]); v = fmaxf(v, 0.f); }
        if (!real) v = 0.f;
        const unsigned short hv = f2bf(v);
        C[(size_t)row * CS + col] = hv;
        if (EPI == EPI_STATS) {
          const float vr = bf2f(hv);
          s += vr;
          q = fmaf(vr, vr, q);
        }
      }
    }
    if (EPI == EPI_STATS) {
      s += __shfl_xor(s, 16); s += __shfl_xor(s, 32);
      q += __shfl_xor(q, 16); q += __shfl_xor(q, 32);
      if (lane < 16) {
        atomicAdd(&sum[col], s);
        atomicAdd(&sumsq[col], q);
      }
    }
  }
}

// ---------------------------------------------------------------------------
// Last GEMM: out[16384][18] (f32) = ovec_bf @ lastWt^T + lastb.
// BM=128, BN=64, WM=4, WN=1, K=256, grid (1,128).
__global__ __launch_bounds__(256) void gemm_last(
    const unsigned short* __restrict__ A, const unsigned short* __restrict__ Wt,
    const float* __restrict__ bias, float* __restrict__ out)
{
  __shared__ unsigned short As[128 * 32];
  __shared__ unsigned short Bs[64 * 32];
  const int row0 = blockIdx.y * 128;
  const int tid = threadIdx.x;
  const int wid = tid >> 6, lane = tid & 63;
  const int arow = tid >> 2;
  const int kcol = (tid & 3) * 8;
  const int lr = lane & 15, lk = (lane >> 4) * 8;
  const int lrow = (lane >> 4) * 4;

  f32x4 acc[2][4] = {};
  for (int k0 = 0; k0 < 256; k0 += 32) {
    gload_lds16(A + (size_t)(row0 + arow) * 256 + k0 + kcol, (char*)As + tid * 16);
    gload_lds16(A + (size_t)(row0 + 64 + arow) * 256 + k0 + kcol, (char*)As + 4096 + tid * 16);
    gload_lds16(Wt + (size_t)arow * 256 + k0 + kcol, (char*)Bs + tid * 16);
    __syncthreads();
    bf16x8 a[2], b[4];
    #pragma unroll
    for (int i = 0; i < 2; ++i)
      a[i] = *reinterpret_cast<const bf16x8*>(&As[(wid * 32 + i * 16 + lr) * 32 + lk]);
    #pragma unroll
    for (int j = 0; j < 4; ++j)
      b[j] = *reinterpret_cast<const bf16x8*>(&Bs[(j * 16 + lr) * 32 + lk]);
    #pragma unroll
    for (int i = 0; i < 2; ++i)
      #pragma unroll
      for (int j = 0; j < 4; ++j)
        acc[i][j] = __builtin_amdgcn_mfma_f32_16x16x32_bf16(a[i], b[j], acc[i][j], 0, 0, 0);
    __syncthreads();
  }
  #pragma unroll
  for (int j = 0; j < 2; ++j) {         // cols 0..31 only (18 real)
    const int col = j * 16 + lr;
    if (col >= 18) continue;
    const float bv = bias[col];
    #pragma unroll
    for (int i = 0; i < 2; ++i) {
      #pragma unroll
      for (int r = 0; r < 4; ++r) {
        const int row = row0 + wid * 32 + i * 16 + lrow + r;
        out[(size_t)row * 18 + col] = acc[i][j][r] + bv;
      }
    }
  }
}

// ---------------------------------------------------------------------------
// Gumbel softmax over groups of 8 (bf16 logits).
__global__ void gumbel8(const unsigned short* __restrict__ logit, const float* __restrict__ u,
                        float* __restrict__ out, int u_off, int u_stride)
{
  const int idx = blockIdx.x * 256 + threadIdx.x;
  const int b = idx >> 3, m = idx & 7;
  const unsigned short* lp = logit + (size_t)b * 64 + m * 8;
  const float* up = u + (size_t)b * u_stride + u_off + m * 8;
  float v[8];
  #pragma unroll
  for (int j = 0; j < 8; ++j) {
    const float uu = fminf(fmaxf(up[j], 1e-10f), 0.9999999f);
    v[j] = bf2f(lp[j]) - logf(-logf(uu));
  }
  float mx = v[0];
  #pragma unroll
  for (int j = 1; j < 8; ++j) mx = fmaxf(mx, v[j]);
  float s = 0.f;
  #pragma unroll
  for (int j = 0; j < 8; ++j) { v[j] = expf(v[j] - mx); s += v[j]; }
  const float inv = 1.f / s;
  float* op = out + (size_t)b * 64 + m * 8;
  #pragma unroll
  for (int j = 0; j < 8; ++j) op[j] = v[j] * inv;
}

__global__ void final_select_k(const unsigned short* __restrict__ si, const float* __restrict__ Wf,
                               const float* __restrict__ bias, const float* __restrict__ u,
                               float* __restrict__ fs)
{
  const int idx = blockIdx.x * 256 + threadIdx.x;
  const int b = idx >> 3, j = idx & 7;
  const unsigned short* sp = si + (size_t)b * 256;
  float acc = bias[j];
  for (int k = 0; k < 256; ++k) acc = fmaf(bf2f(sp[k]), Wf[k * 8 + j], acc);
  const float uu = fminf(fmaxf(u[(size_t)b * 8 + j], 1e-10f), 0.9999999f);
  float v = acc - logf(-logf(uu));
  float mx = v;
  #pragma unroll
  for (int d = 1; d < 8; d <<= 1) mx = fmaxf(mx, __shfl_xor(mx, d, 8));
  float e = expf(v - mx);
  float s = e;
  #pragma unroll
  for (int d = 1; d < 8; d <<= 1) s += __shfl_xor(s, d, 8);
  fs[(size_t)b * 8 + j] = e / s;
}

// ---------------------------------------------------------------------------
// Fold mod weights with inline bn1 finalize. grid (8, 8, 9).
__global__ __launch_bounds__(256) void fold_modw_all(
    const float* __restrict__ W, const float* __restrict__ g1,
    const float* __restrict__ b1, const float* __restrict__ modb,
    const float* __restrict__ sum1, const float* __restrict__ sumsq1,
    unsigned short* __restrict__ Wt, float* __restrict__ bias2)
{
  const float invB = 1.f / 16384.f;
  if (blockIdx.z == 8) {
    if (blockIdx.y != 0) return;
    const int m = blockIdx.x, h = threadIdx.x;
    float acc = modb[m * 256 + h];
    for (int d = 0; d < 256; ++d) {
      const float mean = sum1[d] * invB;
      const float var = sumsq1[d] * invB - mean * mean;
      const float r = rsqrtf(var + 1e-5f);
      const float c = b1[m * 256 + d] - mean * r * g1[m * 256 + d];
      acc = fmaf(c, W[((size_t)m * 256 + d) * 256 + h], acc);
    }
    bias2[m * 256 + h] = acc;
    return;
  }
  __shared__ float t[32][33];
  const int m = blockIdx.z, d0 = blockIdx.y * 32, h0 = blockIdx.x * 32;
  const int tx = threadIdx.x & 31, ty = threadIdx.x >> 5;
  #pragma unroll
  for (int p = 0; p < 4; ++p) {
    const int d = d0 + ty + p * 8;
    const float mean = sum1[d] * invB;
    const float var = sumsq1[d] * invB - mean * mean;
    const float r = rsqrtf(var + 1e-5f);
    t[ty + p * 8][tx] = W[((size_t)m * 256 + d) * 256 + h0 + tx] * r * g1[m * 256 + d];
  }
  __syncthreads();
  #pragma unroll
  for (int p = 0; p < 4; ++p) {
    const int h = h0 + ty + p * 8;
    Wt[((size_t)m * 256 + h) * 256 + d0 + tx] = f2bf(t[tx][ty + p * 8]);
  }
}

// bn2 finalize: scale2/shift2 (2048 each).
__global__ void finalize_bn2(const float* __restrict__ sum, const float* __restrict__ sumsq,
                             const float* __restrict__ g, const float* __restrict__ b,
                             float* __restrict__ scale, float* __restrict__ shift)
{
  const int i = blockIdx.x * 256 + threadIdx.x;
  const float invB = 1.f / 16384.f;
  const float m = sum[i] * invB;
  const float v = sumsq[i] * invB - m * m;
  const float r = rsqrtf(v + 1e-5f);
  const float sc = r * g[i];
  scale[i] = sc;
  shift[i] = b[i] - m * sc;
}

// ---------------------------------------------------------------------------
// Cascade: bn2 apply (precomputed scale/shift) + 3 select rounds + final mix.
// One wave per sample; writes ovec bf16. No LDS, no block sync, no reduce.
__global__ __launch_bounds__(256) void final_cascade(
    const unsigned short* __restrict__ H, const float* __restrict__ scale2,
    const float* __restrict__ shift2, const float* __restrict__ gs0,
    const float* __restrict__ gs1, const float* __restrict__ gs2,
    const float* __restrict__ fs, unsigned short* __restrict__ ovec)
{
  const int wave = threadIdx.x >> 6, lane = threadIdx.x & 63;
  const int b = __builtin_amdgcn_readfirstlane(blockIdx.x * 4 + wave);
  const int c0 = lane << 2;

  float prev[8][4];
  #pragma unroll
  for (int m = 0; m < 8; ++m) {
    const int gc = m * 256 + c0;
    const ushort4 h = *reinterpret_cast<const ushort4*>(&H[(size_t)b * 2048 + gc]);
    const float4 sc = *reinterpret_cast<const float4*>(&scale2[gc]);
    const float4 sh = *reinterpret_cast<const float4*>(&shift2[gc]);
    prev[m][0] = bf2f(h.x) * sc.x + sh.x;
    prev[m][1] = bf2f(h.y) * sc.y + sh.y;
    prev[m][2] = bf2f(h.z) * sc.z + sh.z;
    prev[m][3] = bf2f(h.w) * sc.w + sh.w;
  }

  const float* sel0 = gs2 + (size_t)b * 64;  // selects[0] = gsels[2]
  const float* sel1 = gs1 + (size_t)b * 64;
  const float* sel2 = gs0 + (size_t)b * 64;
  #pragma unroll
  for (int l = 0; l < 3; ++l) {
    const float* sp = (l == 0) ? sel0 : (l == 1) ? sel1 : sel2;
    float nw[8][4];
    #pragma unroll
    for (int m = 0; m < 8; ++m) {
      float a0 = 0.f, a1 = 0.f, a2 = 0.f, a3 = 0.f;
      #pragma unroll
      for (int k = 0; k < 8; ++k) {
        const float s = sp[m * 8 + k];   // wave-uniform scalar load
        a0 = fmaf(s, prev[k][0], a0);
        a1 = fmaf(s, prev[k][1], a1);
        a2 = fmaf(s, prev[k][2], a2);
        a3 = fmaf(s, prev[k][3], a3);
      }
      nw[m][0] = fmaxf(a0, 0.f); nw[m][1] = fmaxf(a1, 0.f);
      nw[m][2] = fmaxf(a2, 0.f); nw[m][3] = fmaxf(a3, 0.f);
    }
    #pragma unroll
    for (int m = 0; m < 8; ++m)
      #pragma unroll
      for (int c = 0; c < 4; ++c)
        prev[m][c] = nw[m][c];
  }

  const float* fp = fs + (size_t)b * 8;
  float ov[4] = {0.f, 0.f, 0.f, 0.f};
  #pragma unroll
  for (int m = 0; m < 8; ++m) {
    const float s = fp[m];               // wave-uniform scalar load
    ov[0] = fmaf(s, prev[m][0], ov[0]);
    ov[1] = fmaf(s, prev[m][1], ov[1]);
    ov[2] = fmaf(s, prev[m][2], ov[2]);
    ov[3] = fmaf(s, prev[m][3], ov[3]);
  }
  ushort4 o;
  o.x = f2bf(ov[0]); o.y = f2bf(ov[1]); o.z = f2bf(ov[2]); o.w = f2bf(ov[3]);
  *reinterpret_cast<ushort4*>(&ovec[(size_t)b * 256 + c0]) = o;
}

extern "C" void kernel_launch(void* const* d_in, const int* in_sizes, int n_in,
                              void* d_out, int out_size, void* d_ws, size_t ws_size,
                              hipStream_t stream)
{
  (void)in_sizes; (void)n_in; (void)out_size; (void)ws_size;
  const float* x       = (const float*)d_in[0];
  const float* embi    = (const float*)d_in[1];
  const float* u_sel   = (const float*)d_in[2];
  const float* u_fin   = (const float*)d_in[3];
  const float* base_W0 = (const float*)d_in[4];
  const float* base_b0 = (const float*)d_in[5];
  const float* base_W1 = (const float*)d_in[6];
  const float* base_b1 = (const float*)d_in[7];
  const float* em_W0   = (const float*)d_in[8];
  const float* em_b0   = (const float*)d_in[9];
  const float* gat_W0  = (const float*)d_in[10];
  const float* gat_b0  = (const float*)d_in[11];
  const float* gat_W1  = (const float*)d_in[12];
  const float* gat_b1  = (const float*)d_in[13];
  const float* sel_W   = (const float*)d_in[14];
  const float* sel_b   = (const float*)d_in[15];
  const float* selF_W  = (const float*)d_in[16];
  const float* selF_b  = (const float*)d_in[17];
  const float* cond_W  = (const float*)d_in[18];
  const float* cond_b  = (const float*)d_in[19];
  const float* mod_W   = (const float*)d_in[20];
  const float* mod_b   = (const float*)d_in[21];
  const float* last_W  = (const float*)d_in[22];
  const float* last_b  = (const float*)d_in[23];
  const float* bn1_g   = (const float*)d_in[24];
  const float* bn1_b   = (const float*)d_in[25];
  const float* bn2_g   = (const float*)d_in[26];
  const float* bn2_b   = (const float*)d_in[27];

  // --- workspace layout (byte offsets) ---
  char* WSB = (char*)d_ws;
  unsigned short* h_big    = (unsigned short*)(WSB + 0);          // 16384x2048 bf16
  unsigned short* h1       = (unsigned short*)(WSB + 67108864);   // 16384x416
  unsigned short* ovec_bf  = (unsigned short*)(WSB + 67108864);   // 16384x256 (overlaps dead h1)
  unsigned short* x_bf     = (unsigned short*)(WSB + 80740352);   // 16384x128
  unsigned short* e_bf     = (unsigned short*)(WSB + 84934656);   // 16384x128
  unsigned short* emb_bf   = (unsigned short*)(WSB + 89128960);   // 16384x256
  unsigned short* si_bf    = (unsigned short*)(WSB + 97517568);   // 16384x256
  unsigned short* out_bf   = (unsigned short*)(WSB + 105906176);  // 16384x256
  unsigned short* logit_bf = (unsigned short*)(WSB + 114294784);  // 16384x64
  float* gs0   = (float*)(WSB + 116391936);  // 16384x64
  float* gs1   = (float*)(WSB + 120586240);
  float* gs2   = (float*)(WSB + 124780544);
  float* bufFs = (float*)(WSB + 128974848);  // 16384x8
  unsigned short* W0t   = (unsigned short*)(WSB + 129499136);  // 512x128
  unsigned short* emW0t = (unsigned short*)(WSB + 129630208);  // 512x128
  unsigned short* W1t   = (unsigned short*)(WSB + 129761280);  // 256x416
  unsigned short* g0t   = (unsigned short*)(WSB + 129974272);  // 256x416
  unsigned short* g1t   = (unsigned short*)(WSB + 130187264);  // 256x256
  unsigned short* selWt = (unsigned short*)(WSB + 130318336);  // 3x64x256
  unsigned short* condWt= (unsigned short*)(WSB + 130416640);  // 3x256x64
  unsigned short* modWt = (unsigned short*)(WSB + 130514944);  // 8x256x256
  float* bias2  = (float*)(WSB + 131563520);  // 2048
  float* stats  = (float*)(WSB + 131571712);  // 4608 floats
  unsigned short* lastWt = (unsigned short*)(WSB + 131590144); // 64x256 bf16
  float* scale2 = (float*)(WSB + 131622912);  // 2048
  float* shift2 = (float*)(WSB + 131631104);  // 2048
  float* sum1   = stats;        float* sumsq1 = stats + 256;
  float* sum2   = stats + 512;  float* sumsq2 = stats + 2560;

  const dim3 blk(256);
  // fused prep (converts + weight transposes + stats zero)
  prep_all<<<dim3(4601), blk, 0, stream>>>(
      x, embi, base_W0, em_W0, base_W1, gat_W0, gat_W1, sel_W, cond_W, last_W,
      x_bf, e_bf, W0t, emW0t, W1t, g0t, g1t, selWt, condWt, lastWt, stats);

  // base MLP: x -> relu -> out (fused bn1 stats)
  gemm_bf16<128, 2, 2, EPI_RELU, false><<<dim3(4, 128), blk, 0, stream>>>(
      x_bf, 128, W0t, base_b0, h1, 416, 400, 416, 128, nullptr, nullptr, nullptr);
  gemm_bf16<128, 2, 2, EPI_STATS, false><<<dim3(2, 128), blk, 0, stream>>>(
      h1, 416, W1t, base_b1, out_bf, 256, 256, 256, 416, nullptr, sum1, sumsq1);
  // embedding / gating
  gemm_bf16<128, 2, 2, EPI_RELU, false><<<dim3(4, 128), blk, 0, stream>>>(
      e_bf, 128, emW0t, em_b0, h1, 416, 400, 416, 128, nullptr, nullptr, nullptr);
  gemm_bf16<128, 2, 2, EPI_RELU, false><<<dim3(2, 128), blk, 0, stream>>>(
      h1, 416, g0t, gat_b0, si_bf, 256, 256, 256, 416, nullptr, nullptr, nullptr);
  gemm_bf16<128, 2, 2, EPI_NONE, false><<<dim3(2, 128), blk, 0, stream>>>(
      si_bf, 256, g1t, gat_b1, emb_bf, 256, 256, 256, 256, nullptr, nullptr, nullptr);
  // select loop
  float* gs[3] = {gs0, gs1, gs2};
  for (int i = 0; i < 3; ++i) {
    if (i == 0)
      gemm_bf16<64, 4, 1, EPI_TANH, true><<<dim3(1, 128), blk, 0, stream>>>(
          emb_bf, 256, selWt, sel_b, logit_bf, 64, 64, 64, 256, nullptr, nullptr, nullptr);
    else
      gemm_bf16<64, 4, 1, EPI_TANH, false><<<dim3(1, 128), blk, 0, stream>>>(
          si_bf, 256, selWt + i * 16384, sel_b + i * 64, logit_bf, 64, 64, 64, 256, nullptr, nullptr, nullptr);
    gumbel8<<<dim3(512), blk, 0, stream>>>(logit_bf, u_sel, gs[i], i * 64, 192);
    gemm_bf16<128, 2, 2, EPI_COND, false><<<dim3(2, 128), blk, 0, stream>>>(
        logit_bf, 64, condWt + i * 16384, cond_b + i * 256, si_bf, 256, 256, 256, 64, emb_bf, nullptr, nullptr);
  }
  final_select_k<<<dim3(512), blk, 0, stream>>>(si_bf, selF_W, selF_b, u_fin, bufFs);
  // bn1 finalize + mod weight fold + bias2 (one kernel)
  fold_modw_all<<<dim3(8, 8, 9), blk, 0, stream>>>(
      mod_W, bn1_g, bn1_b, mod_b, sum1, sumsq1, modWt, bias2);
  // mod einsum as one 16384 x 2048 x 256 GEMM (fused bn2 stats)
  gemm_bf16<128, 2, 2, EPI_STATS, false><<<dim3(16, 128), blk, 0, stream>>>(
      out_bf, 256, modWt, bias2, h_big, 2048, 2048, 2048, 256, nullptr, sum2, sumsq2);
  finalize_bn2<<<dim3(8), blk, 0, stream>>>(sum2, sumsq2, bn2_g, bn2_b, scale2, shift2);
  // cascade -> ovec (bf16)
  final_cascade<<<dim3(4096), blk, 0, stream>>>(
      h_big, scale2, shift2, gs0, gs1, gs2, bufFs, ovec_bf);
  // last GEMM (MFMA) -> d_out f32
  gemm_last<<<dim3(1, 128), blk, 0, stream>>>(ovec_bf, lastWt, last_b, (float*)d_out);
}